// Round 9
// baseline (897.271 us; speedup 1.0000x reference)
//
#include <hip/hip_runtime.h>
#include <stdint.h>
#include <stddef.h>

// Problem constants (reference: NB=4, B=16, C=256, L=4096)
#define NBR 4
#define BSZ 16
#define CHN 256
#define LEN 4096
#define NB_B 64            // NBR*BSZ
#define BL   65536         // BSZ*LEN
#define BN_EPS 1e-5f
#define W_EL (NBR*CHN*CHN) // 262144 elements per weight tensor
#define LT   64            // l-tile: 32KB LDS -> 5 blocks/CU

typedef unsigned short ushortT;
typedef unsigned short ushort4_t __attribute__((ext_vector_type(4)));
typedef unsigned short ushort8_t __attribute__((ext_vector_type(8)));
typedef short bf16x8 __attribute__((ext_vector_type(8)));
typedef float f32x4 __attribute__((ext_vector_type(4)));

__device__ __forceinline__ float bf2f(ushortT u) {
    return __uint_as_float(((unsigned)u) << 16);
}
__device__ __forceinline__ ushortT f2bf(float f) {
    unsigned b = __float_as_uint(f);
    return (ushortT)((b + 0x7FFFu + ((b >> 16) & 1u)) >> 16);
}
// order-preserving float->uint encoding (monotone); memset-0 init is below enc(-inf)
__device__ __forceinline__ unsigned encf(float f) {
    unsigned b = __float_as_uint(f);
    return (b & 0x80000000u) ? ~b : (b | 0x80000000u);
}
__device__ __forceinline__ float decf(unsigned u) {
    unsigned b = (u & 0x80000000u) ? (u ^ 0x80000000u) : ~u;
    return __uint_as_float(b);
}

// XCD-aware bijective block swizzle (T1). nwg=4096, nwg%8==0.
// Consecutive blockIdx round-robin across 8 XCDs; give each XCD 8 fixed l-tile
// columns and advance z in order -> W(n) working set stays hot in that XCD's L2.
__device__ __forceinline__ void swz_block(int bid, int& lt, int& z) {
    int xcd = bid & 7;
    int s   = bid >> 3;          // 0..511 sequential within an XCD
    z  = s >> 3;                 // 0..63 (branch-major: n = z>>4 changes every 128 s)
    lt = xcd * 8 + (s & 7);      // this XCD's 8 l-tile columns
}

// LDS swizzle for sX (byte offsets). Rows are 512B (256 c bf16). row in 0..63.
__device__ __forceinline__ int swzX(int row, int cb) {
    return row * 512 + (cb ^ ((row & 7) << 4) ^ (((row >> 3) & 3) << 7));
}

// Stage x-tile [l=64][c=256] into LDS, transposed+converted, swizzled.
// Loads coalesced per wave-instruction (lane -> l).
__device__ __forceinline__ void stage_x_f32(const float* x, ushortT* sX, int z, int lbase, int tid)
{
    const int ls = tid & 63;
    const int gh = tid >> 6;           // 0..3
    const float* xp = x + (size_t)z * CHN * LEN + lbase + ls;
#pragma unroll
    for (int g = 0; g < 8; ++g) {
        int c0 = (gh * 8 + g) * 8;
        ushort8_t u;
#pragma unroll
        for (int i = 0; i < 8; ++i) u[i] = f2bf(xp[(size_t)(c0 + i) * LEN]);
        *(ushort8_t*)((char*)sX + swzX(ls, c0 * 2)) = u;
    }
}

// Fused-agg staging for ogemm: sX[l][c] = f2bf( sum_j aj[j] * v[j,b,c,l] )
__device__ __forceinline__ void stage_agg(const ushortT* v, ushortT* sX, const float aj[4],
                                          int b_, int lbase, int tid)
{
    const int ls = tid & 63;
    const int gh = tid >> 6;
    const ushortT* vp0 = v + (size_t)(0 * BSZ + b_) * CHN * LEN + lbase + ls;
    const ushortT* vp1 = v + (size_t)(1 * BSZ + b_) * CHN * LEN + lbase + ls;
    const ushortT* vp2 = v + (size_t)(2 * BSZ + b_) * CHN * LEN + lbase + ls;
    const ushortT* vp3 = v + (size_t)(3 * BSZ + b_) * CHN * LEN + lbase + ls;
#pragma unroll
    for (int g = 0; g < 8; ++g) {
        int c0 = (gh * 8 + g) * 8;
        ushort8_t u;
#pragma unroll
        for (int i = 0; i < 8; ++i) {
            size_t o = (size_t)(c0 + i) * LEN;
            float s = aj[0] * bf2f(vp0[o]) + aj[1] * bf2f(vp1[o])
                    + aj[2] * bf2f(vp2[o]) + aj[3] * bf2f(vp3[o]);
            u[i] = f2bf(s);
        }
        *(ushort8_t*)((char*)sX + swzX(ls, c0 * 2)) = u;
    }
}

// One K-chunk (64 c) of MFMA. W B-fragments from global in PRE-PACKED fragment
// order Wb2[ob][cb][lane][8] -> base + lane*16B = coalesced 1KB dwordx4 (L2).
// A = x (M=l) from LDS. acc[mf][nf] row=l col=o. Wave covers 64l x 32o.
__device__ __forceinline__ void mfma_chunk_frag(const ushortT* sX, const ushortT* __restrict__ Wb2,
                                                int otile, f32x4 acc[4][2],
                                                int wc, int lane, int kb)
{
    const int am = lane & 15;
    const int kg = (lane >> 4) * 16;   // byte offset of this lane's k-group (LDS)
#pragma unroll
    for (int s = 0; s < 2; ++s) {
        const int cb = kb * 2 + s;
        bf16x8 a[4], b[2];
#pragma unroll
        for (int nf = 0; nf < 2; ++nf) {
            const int ob = otile * 8 + wc * 2 + nf;
            b[nf] = *(const bf16x8*)(Wb2 + (((size_t)ob * 8 + cb) * 64 + lane) * 8);
        }
#pragma unroll
        for (int mf = 0; mf < 4; ++mf)
            a[mf] = *(const bf16x8*)((const char*)sX + swzX(am + mf * 16, kb * 128 + s * 64 + kg));
#pragma unroll
        for (int mf = 0; mf < 4; ++mf)
#pragma unroll
            for (int nf = 0; nf < 2; ++nf)
                acc[mf][nf] = __builtin_amdgcn_mfma_f32_16x16x32_bf16(a[mf], b[nf], acc[mf][nf], 0, 0, 0);
    }
}

// ---------------------------------------------------------------------------
// QKV fused: stage x-tile (1 barrier), then 6 barrier-free GEMM-tiles.
// 4 waves each own a 32-o column strip. 32KB LDS -> 5 blocks/CU.
// XCD-swizzled block mapping keeps each XCD's W working set L2-resident.
// ---------------------------------------------------------------------------
__global__ __launch_bounds__(256, 5)
void qkv_kernel(const float* __restrict__ x, const ushortT* __restrict__ Wbf,
                const float* __restrict__ bv,
                float* __restrict__ qsum, unsigned* __restrict__ qmax,
                float* __restrict__ ksum, unsigned* __restrict__ kmax,
                ushortT* __restrict__ vbuf)
{
    __shared__ ushortT sX[LT * 256];    // 32 KiB
    const int tid = threadIdx.x;
    const int lane = tid & 63;
    const int wc = tid >> 6;            // wave -> o strip (0..3)
    int lt, z;
    swz_block(blockIdx.x, lt, z);
    const int lbase = lt * LT;
    const int n = z >> 4;

    stage_x_f32(x, sX, z, lbase, tid);
    __syncthreads();                    // the only barrier

    const f32x4 z4 = {0.f, 0.f, 0.f, 0.f};

    for (int w = 0; w < 3; ++w) {
        const ushortT* Wb2 = Wbf + ((size_t)w * NBR + n) * CHN * CHN;
        for (int ot = 0; ot < 2; ++ot) {
            f32x4 acc[4][2];
#pragma unroll
            for (int mf = 0; mf < 4; ++mf)
#pragma unroll
                for (int nf = 0; nf < 2; ++nf) acc[mf][nf] = z4;
#pragma unroll
            for (int kb = 0; kb < 4; ++kb)
                mfma_chunk_frag(sX, Wb2, ot, acc, wc, lane, kb);

            const int obase = ot * 128 + wc * 32;
            if (w < 2) {
                float* rs = (w == 0) ? qsum : ksum;
                unsigned* rm = (w == 0) ? qmax : kmax;
#pragma unroll
                for (int nf = 0; nf < 2; ++nf) {
                    float s = 0.f, m = -3.4e38f;
#pragma unroll
                    for (int mf = 0; mf < 4; ++mf)
#pragma unroll
                        for (int r = 0; r < 4; ++r) {
                            float v = acc[mf][nf][r];
                            s += v; m = fmaxf(m, v);
                        }
                    s += __shfl_xor(s, 16); s += __shfl_xor(s, 32);
                    m = fmaxf(m, __shfl_xor(m, 16)); m = fmaxf(m, __shfl_xor(m, 32));
                    if (lane < 16) {
                        int o = obase + nf * 16 + lane;
                        atomicAdd(&rs[z * CHN + o], s);
                        atomicMax(&rm[z * CHN + o], encf(m));
                    }
                }
            } else {
#pragma unroll
                for (int nf = 0; nf < 2; ++nf) {
                    int o = obase + nf * 16 + (lane & 15);
                    float bvv = bv[n * CHN + o];
#pragma unroll
                    for (int mf = 0; mf < 4; ++mf) {
                        int l = lbase + mf * 16 + ((lane >> 4) << 2);
                        ushort4_t u;
#pragma unroll
                        for (int r = 0; r < 4; ++r) u[r] = f2bf(acc[mf][nf][r] + bvv);
                        *(ushort4_t*)(vbuf + (size_t)(z * CHN + o) * LEN + l) = u;
                    }
                }
            }
        }
    }
}

// ---------------------------------------------------------------------------
// O GEMM with FUSED aggregation: stage combines 4 v-slices with attn weights
// in-register, then barrier-free Wo GEMM -> out_pre[z][c][l] + BN stats.
// Same XCD-swizzled block mapping.
// ---------------------------------------------------------------------------
__global__ __launch_bounds__(256, 5)
void ogemm_kernel(const ushortT* __restrict__ v, const ushortT* __restrict__ Wbo,
                  const float* __restrict__ attn, const float* __restrict__ bo_,
                  float* __restrict__ bnsum, float* __restrict__ bnss,
                  ushortT* __restrict__ outpre)
{
    __shared__ ushortT sX[LT * 256];
    const int tid = threadIdx.x;
    const int lane = tid & 63;
    const int wc = tid >> 6;
    int lt, z;
    swz_block(blockIdx.x, lt, z);
    const int lbase = lt * LT;
    const int n = z >> 4;          // output branch i
    const int b_ = z & 15;
    const ushortT* Wb2 = Wbo + (size_t)n * CHN * CHN;

    float aj[4];
#pragma unroll
    for (int j = 0; j < 4; ++j) aj[j] = attn[(n * 4 + j) * BSZ + b_];

    stage_agg(v, sX, aj, b_, lbase, tid);
    __syncthreads();                    // the only barrier

    const f32x4 z4 = {0.f, 0.f, 0.f, 0.f};
    for (int ot = 0; ot < 2; ++ot) {
        f32x4 acc[4][2];
#pragma unroll
        for (int mf = 0; mf < 4; ++mf)
#pragma unroll
            for (int nf = 0; nf < 2; ++nf) acc[mf][nf] = z4;
#pragma unroll
        for (int kb = 0; kb < 4; ++kb)
            mfma_chunk_frag(sX, Wb2, ot, acc, wc, lane, kb);

        const int obase = ot * 128 + wc * 32;
#pragma unroll
        for (int nf = 0; nf < 2; ++nf) {
            int o = obase + nf * 16 + (lane & 15);
            float bb = bo_[n * CHN + o];
            float s = 0.f, q2 = 0.f;
#pragma unroll
            for (int mf = 0; mf < 4; ++mf) {
                int l = lbase + mf * 16 + ((lane >> 4) << 2);
                ushort4_t u;
#pragma unroll
                for (int r = 0; r < 4; ++r) {
                    float vv = acc[mf][nf][r] + bb;
                    u[r] = f2bf(vv);
                    s += vv; q2 += vv * vv;
                }
                *(ushort4_t*)(outpre + (size_t)(z * CHN + o) * LEN + l) = u;
            }
            s += __shfl_xor(s, 16); s += __shfl_xor(s, 32);
            q2 += __shfl_xor(q2, 16); q2 += __shfl_xor(q2, 32);
            if (lane < 16) {
                atomicAdd(&bnsum[n * CHN + o], s);
                atomicAdd(&bnss[n * CHN + o], q2);
            }
        }
    }
}

// convert all 4 weight tensors fp32 -> bf16 in MFMA-FRAGMENT order:
// Wbf[w][n][ob][cb][lane][8] with o = ob*16 + (lane&15), c = cb*32 + (lane>>4)*8 + j
__global__ void wcvt_kernel(const float* __restrict__ Wq, const float* __restrict__ Wk,
                            const float* __restrict__ Wv, const float* __restrict__ Wo,
                            ushortT* __restrict__ Wbf)
{
    int t = blockIdx.x * 256 + threadIdx.x;    // one thread per 8-elem fragment slice
    if (t < 4 * (W_EL / 8)) {
        const float* srcs[4] = {Wq, Wk, Wv, Wo};
        int w    = t >> 15;          // W_EL/8 = 32768 per tensor
        int r    = t & 32767;
        int lane = r & 63;
        int cb   = (r >> 6) & 7;
        int ob   = (r >> 9) & 15;
        int n    = r >> 13;
        const float* src = srcs[w] + (size_t)n * CHN * CHN;
        int o = ob * 16 + (lane & 15);
        int c = cb * 32 + (lane >> 4) * 8;
        float4 f0 = *(const float4*)(src + (size_t)o * CHN + c);
        float4 f1 = *(const float4*)(src + (size_t)o * CHN + c + 4);
        ushort8_t u = {f2bf(f0.x), f2bf(f0.y), f2bf(f0.z), f2bf(f0.w),
                       f2bf(f1.x), f2bf(f1.y), f2bf(f1.z), f2bf(f1.w)};
        *(ushort8_t*)(Wbf + ((size_t)w * NBR + n) * CHN * CHN
                          + (((size_t)ob * 8 + cb) * 64 + lane) * 8) = u;
    }
}

// ---------------------------------------------------------------------------
// attention coefficients: scores[i,j,b] = (sum_c sq*sk) * edge_w[i,j] / 64
// attn[i,j,b] = softmax_j(scores) * softmax(branch_imp)[j]
// sq = qsum/L + dec(qmax) + 2*bq  (mean+max, bias shifts both by bq)
// ---------------------------------------------------------------------------
__global__ void attn_kernel(const float* __restrict__ qsum, const unsigned* __restrict__ qmax,
                            const float* __restrict__ ksum, const unsigned* __restrict__ kmax,
                            const float* __restrict__ bq, const float* __restrict__ bk,
                            const float* __restrict__ edge, const float* __restrict__ bimp,
                            float* __restrict__ attn)
{
    __shared__ float sc[NBR][NBR][BSZ];
    int tid = threadIdx.x;           // 256 threads == 4*4*16
    int i = tid >> 6, j = (tid >> 4) & 3, b = tid & 15;
    float s = 0.f;
    const float invL = 1.0f / (float)LEN;
    for (int c = 0; c < CHN; ++c) {
        int qi = (i * BSZ + b) * CHN + c;
        int ki = (j * BSZ + b) * CHN + c;
        float sq = qsum[qi] * invL + decf(qmax[qi]) + 2.f * bq[i * CHN + c];
        float sk = ksum[ki] * invL + decf(kmax[ki]) + 2.f * bk[j * CHN + c];
        s += sq * sk;
    }
    sc[i][j][b] = s * edge[i * 4 + j] * (1.0f / 64.0f);
    __syncthreads();
    if (tid < 64) {
        int ii = tid >> 4, bb = tid & 15;
        float m = -3.4e38f;
        for (int jj = 0; jj < 4; ++jj) m = fmaxf(m, sc[ii][jj][bb]);
        float e[4]; float sum = 0.f;
        for (int jj = 0; jj < 4; ++jj) { e[jj] = __expf(sc[ii][jj][bb] - m); sum += e[jj]; }
        float bm = fmaxf(fmaxf(bimp[0], bimp[1]), fmaxf(bimp[2], bimp[3]));
        float be[4]; float bs = 0.f;
        for (int jj = 0; jj < 4; ++jj) { be[jj] = __expf(bimp[jj] - bm); bs += be[jj]; }
        for (int jj = 0; jj < 4; ++jj)
            attn[(ii * 4 + jj) * BSZ + bb] = (e[jj] / sum) * (be[jj] / bs);
    }
}

// finalize BN affine: scale = gamma*rsqrt(var+eps), shift = beta - mean*scale
__global__ void bnfin_kernel(const float* __restrict__ bnsum, const float* __restrict__ bnss,
                             const float* __restrict__ gamma, const float* __restrict__ beta,
                             float* __restrict__ scl, float* __restrict__ shf)
{
    int t = blockIdx.x * blockDim.x + threadIdx.x;   // 0..1023 = n*256+c
    if (t < NBR * CHN) {
        const float inv = 1.0f / (float)BL;
        float mean = bnsum[t] * inv;
        float var = bnss[t] * inv - mean * mean;
        float rs = rsqrtf(var + BN_EPS);
        float s = gamma[t] * rs;
        scl[t] = s;
        shf[t] = beta[t] - mean * s;
    }
}

// out = relu(out_pre*scale + shift) + x
__global__ __launch_bounds__(256)
void final_kernel(const ushortT* __restrict__ outpre, const float* __restrict__ x,
                  const float* __restrict__ scl, const float* __restrict__ shf,
                  float* __restrict__ out)
{
    const long long U = (long long)NB_B * CHN * (LEN / 8);   // 8,388,608 units of 8
    for (long long u = (long long)blockIdx.x * blockDim.x + threadIdx.x; u < U;
         u += (long long)gridDim.x * blockDim.x) {
        int l0 = (int)(u & 511) * 8;
        int c  = (int)(u >> 9) & 255;
        int zz = (int)(u >> 17);          // n*16+b
        int n  = zz >> 4;
        size_t base = ((size_t)zz * CHN + c) * LEN + l0;
        ushort8_t op = *(const ushort8_t*)(outpre + base);
        float4 x0 = *(const float4*)(x + base);
        float4 x1 = *(const float4*)(x + base + 4);
        float sc = scl[n * CHN + c];
        float sh = shf[n * CHN + c];
        float xr[8] = {x0.x, x0.y, x0.z, x0.w, x1.x, x1.y, x1.z, x1.w};
        float res[8];
#pragma unroll
        for (int e = 0; e < 8; ++e) {
            float bn = bf2f(op[e]) * sc + sh;
            res[e] = fmaxf(bn, 0.f) + xr[e];
        }
        float4 o0 = {res[0], res[1], res[2], res[3]};
        float4 o1 = {res[4], res[5], res[6], res[7]};
        *(float4*)(out + base) = o0;
        *(float4*)(out + base + 4) = o1;
    }
}

extern "C" void kernel_launch(void* const* d_in, const int* in_sizes, int n_in,
                              void* d_out, int out_size, void* d_ws, size_t ws_size,
                              hipStream_t stream)
{
    const float* x     = (const float*)d_in[0];
    const float* Wq    = (const float*)d_in[1];
    const float* bq    = (const float*)d_in[2];
    const float* Wk    = (const float*)d_in[3];
    const float* bk    = (const float*)d_in[4];
    const float* Wv    = (const float*)d_in[5];
    const float* bv    = (const float*)d_in[6];
    const float* Wo    = (const float*)d_in[7];
    const float* bo    = (const float*)d_in[8];
    const float* gamma = (const float*)d_in[9];
    const float* beta  = (const float*)d_in[10];
    const float* edge  = (const float*)d_in[11];
    const float* bimp  = (const float*)d_in[12];

    char* ws = (char*)d_ws;
    const size_t P_BYTES = (size_t)NBR * BSZ * CHN * LEN * 2;   // 128 MiB (bf16)
    ushortT* outpre = (ushortT*)ws;          // out_pre staging (ws[0:128Mi])
    size_t off = P_BYTES;
    float*    qsum = (float*)(ws + off);    off += 65536;
    unsigned* qmax = (unsigned*)(ws + off); off += 65536;
    float*    ksum = (float*)(ws + off);    off += 65536;
    unsigned* kmax = (unsigned*)(ws + off); off += 65536;
    float*    attn = (float*)(ws + off);    off += 1024;
    float*    bnsum= (float*)(ws + off);    off += 4096;
    float*    bnss = (float*)(ws + off);    off += 4096;
    float*    scl  = (float*)(ws + off);    off += 4096;
    float*    shf  = (float*)(ws + off);    off += 4096;

    // zero the small accumulators (sum=0; max uses encoding where 0 < enc(-inf))
    hipMemsetAsync(ws + P_BYTES, 0, off - P_BYTES, stream);

    // d_out scratch (all dead before final_kernel rewrites d_out):
    //   [0, 128Mi):    v (bf16, [z][c][l]) written by qkv, read by ogemm
    //   [128Mi, +2Mi): Wbf (bf16 weights, fragment order) written by wcvt
    ushortT* vbuf = (ushortT*)d_out;
    ushortT* Wbf  = (ushortT*)((char*)d_out + ((size_t)134217728));
    float*   outf = (float*)d_out;

    wcvt_kernel<<<(4 * (W_EL / 8) + 255) / 256, 256, 0, stream>>>(Wq, Wk, Wv, Wo, Wbf);

    const int NWG = (LEN / LT) * NB_B;   // 4096, %8 == 0
    qkv_kernel<<<NWG, 256, 0, stream>>>(x, Wbf, bv, qsum, qmax, ksum, kmax, vbuf);
    attn_kernel<<<1, 256, 0, stream>>>(qsum, qmax, ksum, kmax, bq, bk, edge, bimp, attn);
    ogemm_kernel<<<NWG, 256, 0, stream>>>(vbuf, Wbf + (size_t)3 * W_EL, attn, bo, bnsum, bnss, outpre);
    bnfin_kernel<<<4, 256, 0, stream>>>(bnsum, bnss, gamma, beta, scl, shf);
    final_kernel<<<8192, 256, 0, stream>>>(outpre, x, scl, shf, outf);
}

// Round 10
// 893.554 us; speedup vs baseline: 1.0042x; 1.0042x over previous
//
#include <hip/hip_runtime.h>
#include <stdint.h>
#include <stddef.h>

// Problem constants (reference: NB=4, B=16, C=256, L=4096)
#define NBR 4
#define BSZ 16
#define CHN 256
#define LEN 4096
#define NB_B 64            // NBR*BSZ
#define BL   65536         // BSZ*LEN
#define BN_EPS 1e-5f
#define W_EL (NBR*CHN*CHN) // 262144 elements per weight tensor
#define LT   64            // l-tile: 32KB LDS -> 5 blocks/CU

typedef unsigned short ushortT;
typedef unsigned short ushort4_t __attribute__((ext_vector_type(4)));
typedef unsigned short ushort8_t __attribute__((ext_vector_type(8)));
typedef short bf16x8 __attribute__((ext_vector_type(8)));
typedef float f32x4 __attribute__((ext_vector_type(4)));

__device__ __forceinline__ float bf2f(ushortT u) {
    return __uint_as_float(((unsigned)u) << 16);
}
__device__ __forceinline__ ushortT f2bf(float f) {
    unsigned b = __float_as_uint(f);
    return (ushortT)((b + 0x7FFFu + ((b >> 16) & 1u)) >> 16);
}
// order-preserving float->uint encoding (monotone); memset-0 init is below enc(-inf)
__device__ __forceinline__ unsigned encf(float f) {
    unsigned b = __float_as_uint(f);
    return (b & 0x80000000u) ? ~b : (b | 0x80000000u);
}
__device__ __forceinline__ float decf(unsigned u) {
    unsigned b = (u & 0x80000000u) ? (u ^ 0x80000000u) : ~u;
    return __uint_as_float(b);
}

// XCD-aware bijective block swizzle (T1). nwg=4096, nwg%8==0.
// Consecutive blockIdx round-robin across 8 XCDs; give each XCD 8 fixed l-tile
// columns and advance z in order -> W(n) working set stays hot in that XCD's L2.
__device__ __forceinline__ void swz_block(int bid, int& lt, int& z) {
    int xcd = bid & 7;
    int s   = bid >> 3;          // 0..511 sequential within an XCD
    z  = s >> 3;                 // 0..63 (branch-major: n = z>>4 changes every 128 s)
    lt = xcd * 8 + (s & 7);      // this XCD's 8 l-tile columns
}

// LDS swizzle for sX (byte offsets). Rows are 512B (256 c bf16). row in 0..63.
__device__ __forceinline__ int swzX(int row, int cb) {
    return row * 512 + (cb ^ ((row & 7) << 4) ^ (((row >> 3) & 3) << 7));
}

// Stage x-tile [l=64][c=256] into LDS, transposed+converted, swizzled.
// Loads coalesced per wave-instruction (lane -> l).
__device__ __forceinline__ void stage_x_f32(const float* x, ushortT* sX, int z, int lbase, int tid)
{
    const int ls = tid & 63;
    const int gh = tid >> 6;           // 0..3
    const float* xp = x + (size_t)z * CHN * LEN + lbase + ls;
#pragma unroll
    for (int g = 0; g < 8; ++g) {
        int c0 = (gh * 8 + g) * 8;
        ushort8_t u;
#pragma unroll
        for (int i = 0; i < 8; ++i) u[i] = f2bf(xp[(size_t)(c0 + i) * LEN]);
        *(ushort8_t*)((char*)sX + swzX(ls, c0 * 2)) = u;
    }
}

// Fused-agg staging for ogemm: sX[l][c] = f2bf( sum_j aj[j] * v[j,b,c,l] )
__device__ __forceinline__ void stage_agg(const ushortT* v, ushortT* sX, const float aj[4],
                                          int b_, int lbase, int tid)
{
    const int ls = tid & 63;
    const int gh = tid >> 6;
    const ushortT* vp0 = v + (size_t)(0 * BSZ + b_) * CHN * LEN + lbase + ls;
    const ushortT* vp1 = v + (size_t)(1 * BSZ + b_) * CHN * LEN + lbase + ls;
    const ushortT* vp2 = v + (size_t)(2 * BSZ + b_) * CHN * LEN + lbase + ls;
    const ushortT* vp3 = v + (size_t)(3 * BSZ + b_) * CHN * LEN + lbase + ls;
#pragma unroll
    for (int g = 0; g < 8; ++g) {
        int c0 = (gh * 8 + g) * 8;
        ushort8_t u;
#pragma unroll
        for (int i = 0; i < 8; ++i) {
            size_t o = (size_t)(c0 + i) * LEN;
            float s = aj[0] * bf2f(vp0[o]) + aj[1] * bf2f(vp1[o])
                    + aj[2] * bf2f(vp2[o]) + aj[3] * bf2f(vp3[o]);
            u[i] = f2bf(s);
        }
        *(ushort8_t*)((char*)sX + swzX(ls, c0 * 2)) = u;
    }
}

// One K-chunk (64 c) of MFMA. W B-fragments from global in PRE-PACKED fragment
// order Wb2[ob][cb][lane][8] -> base + lane*16B = coalesced 1KB dwordx4 (L2).
// A = x (M=l) from LDS. acc[mf][nf] row=l col=o. Wave covers 64l x 32o.
__device__ __forceinline__ void mfma_chunk_frag(const ushortT* sX, const ushortT* __restrict__ Wb2,
                                                int otile, f32x4 acc[4][2],
                                                int wc, int lane, int kb)
{
    const int am = lane & 15;
    const int kg = (lane >> 4) * 16;   // byte offset of this lane's k-group (LDS)
#pragma unroll
    for (int s = 0; s < 2; ++s) {
        const int cb = kb * 2 + s;
        bf16x8 a[4], b[2];
#pragma unroll
        for (int nf = 0; nf < 2; ++nf) {
            const int ob = otile * 8 + wc * 2 + nf;
            b[nf] = *(const bf16x8*)(Wb2 + (((size_t)ob * 8 + cb) * 64 + lane) * 8);
        }
#pragma unroll
        for (int mf = 0; mf < 4; ++mf)
            a[mf] = *(const bf16x8*)((const char*)sX + swzX(am + mf * 16, kb * 128 + s * 64 + kg));
#pragma unroll
        for (int mf = 0; mf < 4; ++mf)
#pragma unroll
            for (int nf = 0; nf < 2; ++nf)
                acc[mf][nf] = __builtin_amdgcn_mfma_f32_16x16x32_bf16(a[mf], b[nf], acc[mf][nf], 0, 0, 0);
    }
}

// ---------------------------------------------------------------------------
// QKV fused: stage x-tile (1 barrier), then 6 barrier-free GEMM-tiles.
// 4 waves each own a 32-o column strip. 32KB LDS -> 5 blocks/CU.
// XCD-swizzled block mapping keeps each XCD's W working set L2-resident.
// ---------------------------------------------------------------------------
__global__ __launch_bounds__(256, 5)
void qkv_kernel(const float* __restrict__ x, const ushortT* __restrict__ Wbf,
                const float* __restrict__ bv,
                float* __restrict__ qsum, unsigned* __restrict__ qmax,
                float* __restrict__ ksum, unsigned* __restrict__ kmax,
                ushortT* __restrict__ vbuf)
{
    __shared__ ushortT sX[LT * 256];    // 32 KiB
    const int tid = threadIdx.x;
    const int lane = tid & 63;
    const int wc = tid >> 6;            // wave -> o strip (0..3)
    int lt, z;
    swz_block(blockIdx.x, lt, z);
    const int lbase = lt * LT;
    const int n = z >> 4;

    stage_x_f32(x, sX, z, lbase, tid);
    __syncthreads();                    // the only barrier

    const f32x4 z4 = {0.f, 0.f, 0.f, 0.f};

    for (int w = 0; w < 3; ++w) {
        const ushortT* Wb2 = Wbf + ((size_t)w * NBR + n) * CHN * CHN;
        for (int ot = 0; ot < 2; ++ot) {
            f32x4 acc[4][2];
#pragma unroll
            for (int mf = 0; mf < 4; ++mf)
#pragma unroll
                for (int nf = 0; nf < 2; ++nf) acc[mf][nf] = z4;
#pragma unroll
            for (int kb = 0; kb < 4; ++kb)
                mfma_chunk_frag(sX, Wb2, ot, acc, wc, lane, kb);

            const int obase = ot * 128 + wc * 32;
            if (w < 2) {
                float* rs = (w == 0) ? qsum : ksum;
                unsigned* rm = (w == 0) ? qmax : kmax;
#pragma unroll
                for (int nf = 0; nf < 2; ++nf) {
                    float s = 0.f, m = -3.4e38f;
#pragma unroll
                    for (int mf = 0; mf < 4; ++mf)
#pragma unroll
                        for (int r = 0; r < 4; ++r) {
                            float v = acc[mf][nf][r];
                            s += v; m = fmaxf(m, v);
                        }
                    s += __shfl_xor(s, 16); s += __shfl_xor(s, 32);
                    m = fmaxf(m, __shfl_xor(m, 16)); m = fmaxf(m, __shfl_xor(m, 32));
                    if (lane < 16) {
                        int o = obase + nf * 16 + lane;
                        atomicAdd(&rs[z * CHN + o], s);
                        atomicMax(&rm[z * CHN + o], encf(m));
                    }
                }
            } else {
#pragma unroll
                for (int nf = 0; nf < 2; ++nf) {
                    int o = obase + nf * 16 + (lane & 15);
                    float bvv = bv[n * CHN + o];
#pragma unroll
                    for (int mf = 0; mf < 4; ++mf) {
                        int l = lbase + mf * 16 + ((lane >> 4) << 2);
                        ushort4_t u;
#pragma unroll
                        for (int r = 0; r < 4; ++r) u[r] = f2bf(acc[mf][nf][r] + bvv);
                        *(ushort4_t*)(vbuf + (size_t)(z * CHN + o) * LEN + l) = u;
                    }
                }
            }
        }
    }
}

// ---------------------------------------------------------------------------
// O GEMM with FUSED aggregation: stage combines 4 v-slices with attn weights
// in-register, then barrier-free Wo GEMM -> out_pre[z][c][l] + BN stats.
// Same XCD-swizzled block mapping.
// ---------------------------------------------------------------------------
__global__ __launch_bounds__(256, 5)
void ogemm_kernel(const ushortT* __restrict__ v, const ushortT* __restrict__ Wbo,
                  const float* __restrict__ attn, const float* __restrict__ bo_,
                  float* __restrict__ bnsum, float* __restrict__ bnss,
                  ushortT* __restrict__ outpre)
{
    __shared__ ushortT sX[LT * 256];
    const int tid = threadIdx.x;
    const int lane = tid & 63;
    const int wc = tid >> 6;
    int lt, z;
    swz_block(blockIdx.x, lt, z);
    const int lbase = lt * LT;
    const int n = z >> 4;          // output branch i
    const int b_ = z & 15;
    const ushortT* Wb2 = Wbo + (size_t)n * CHN * CHN;

    float aj[4];
#pragma unroll
    for (int j = 0; j < 4; ++j) aj[j] = attn[(n * 4 + j) * BSZ + b_];

    stage_agg(v, sX, aj, b_, lbase, tid);
    __syncthreads();                    // the only barrier

    const f32x4 z4 = {0.f, 0.f, 0.f, 0.f};
    for (int ot = 0; ot < 2; ++ot) {
        f32x4 acc[4][2];
#pragma unroll
        for (int mf = 0; mf < 4; ++mf)
#pragma unroll
            for (int nf = 0; nf < 2; ++nf) acc[mf][nf] = z4;
#pragma unroll
        for (int kb = 0; kb < 4; ++kb)
            mfma_chunk_frag(sX, Wb2, ot, acc, wc, lane, kb);

        const int obase = ot * 128 + wc * 32;
#pragma unroll
        for (int nf = 0; nf < 2; ++nf) {
            int o = obase + nf * 16 + (lane & 15);
            float bb = bo_[n * CHN + o];
            float s = 0.f, q2 = 0.f;
#pragma unroll
            for (int mf = 0; mf < 4; ++mf) {
                int l = lbase + mf * 16 + ((lane >> 4) << 2);
                ushort4_t u;
#pragma unroll
                for (int r = 0; r < 4; ++r) {
                    float vv = acc[mf][nf][r] + bb;
                    u[r] = f2bf(vv);
                    s += vv; q2 += vv * vv;
                }
                *(ushort4_t*)(outpre + (size_t)(z * CHN + o) * LEN + l) = u;
            }
            s += __shfl_xor(s, 16); s += __shfl_xor(s, 32);
            q2 += __shfl_xor(q2, 16); q2 += __shfl_xor(q2, 32);
            if (lane < 16) {
                atomicAdd(&bnsum[n * CHN + o], s);
                atomicAdd(&bnss[n * CHN + o], q2);
            }
        }
    }
}

// convert all 4 weight tensors fp32 -> bf16 in MFMA-FRAGMENT order:
// Wbf[w][n][ob][cb][lane][8] with o = ob*16 + (lane&15), c = cb*32 + (lane>>4)*8 + j
__global__ void wcvt_kernel(const float* __restrict__ Wq, const float* __restrict__ Wk,
                            const float* __restrict__ Wv, const float* __restrict__ Wo,
                            ushortT* __restrict__ Wbf)
{
    int t = blockIdx.x * 256 + threadIdx.x;    // one thread per 8-elem fragment slice
    if (t < 4 * (W_EL / 8)) {
        const float* srcs[4] = {Wq, Wk, Wv, Wo};
        int w    = t >> 15;          // W_EL/8 = 32768 per tensor
        int r    = t & 32767;
        int lane = r & 63;
        int cb   = (r >> 6) & 7;
        int ob   = (r >> 9) & 15;
        int n    = r >> 13;
        const float* src = srcs[w] + (size_t)n * CHN * CHN;
        int o = ob * 16 + (lane & 15);
        int c = cb * 32 + (lane >> 4) * 8;
        float4 f0 = *(const float4*)(src + (size_t)o * CHN + c);
        float4 f1 = *(const float4*)(src + (size_t)o * CHN + c + 4);
        ushort8_t u = {f2bf(f0.x), f2bf(f0.y), f2bf(f0.z), f2bf(f0.w),
                       f2bf(f1.x), f2bf(f1.y), f2bf(f1.z), f2bf(f1.w)};
        *(ushort8_t*)(Wbf + ((size_t)w * NBR + n) * CHN * CHN
                          + (((size_t)ob * 8 + cb) * 64 + lane) * 8) = u;
    }
}

// ---------------------------------------------------------------------------
// attention coefficients: scores[i,j,b] = (sum_c sq*sk) * edge_w[i,j] / 64
// attn[i,j,b] = softmax_j(scores) * softmax(branch_imp)[j]
// sq = qsum/L + dec(qmax) + 2*bq  (mean+max, bias shifts both by bq)
// ---------------------------------------------------------------------------
__global__ void attn_kernel(const float* __restrict__ qsum, const unsigned* __restrict__ qmax,
                            const float* __restrict__ ksum, const unsigned* __restrict__ kmax,
                            const float* __restrict__ bq, const float* __restrict__ bk,
                            const float* __restrict__ edge, const float* __restrict__ bimp,
                            float* __restrict__ attn)
{
    __shared__ float sc[NBR][NBR][BSZ];
    int tid = threadIdx.x;           // 256 threads == 4*4*16
    int i = tid >> 6, j = (tid >> 4) & 3, b = tid & 15;
    float s = 0.f;
    const float invL = 1.0f / (float)LEN;
    for (int c = 0; c < CHN; ++c) {
        int qi = (i * BSZ + b) * CHN + c;
        int ki = (j * BSZ + b) * CHN + c;
        float sq = qsum[qi] * invL + decf(qmax[qi]) + 2.f * bq[i * CHN + c];
        float sk = ksum[ki] * invL + decf(kmax[ki]) + 2.f * bk[j * CHN + c];
        s += sq * sk;
    }
    sc[i][j][b] = s * edge[i * 4 + j] * (1.0f / 64.0f);
    __syncthreads();
    if (tid < 64) {
        int ii = tid >> 4, bb = tid & 15;
        float m = -3.4e38f;
        for (int jj = 0; jj < 4; ++jj) m = fmaxf(m, sc[ii][jj][bb]);
        float e[4]; float sum = 0.f;
        for (int jj = 0; jj < 4; ++jj) { e[jj] = __expf(sc[ii][jj][bb] - m); sum += e[jj]; }
        float bm = fmaxf(fmaxf(bimp[0], bimp[1]), fmaxf(bimp[2], bimp[3]));
        float be[4]; float bs = 0.f;
        for (int jj = 0; jj < 4; ++jj) { be[jj] = __expf(bimp[jj] - bm); bs += be[jj]; }
        for (int jj = 0; jj < 4; ++jj)
            attn[(ii * 4 + jj) * BSZ + bb] = (e[jj] / sum) * (be[jj] / bs);
    }
}

// finalize BN affine: scale = gamma*rsqrt(var+eps), shift = beta - mean*scale
__global__ void bnfin_kernel(const float* __restrict__ bnsum, const float* __restrict__ bnss,
                             const float* __restrict__ gamma, const float* __restrict__ beta,
                             float* __restrict__ scl, float* __restrict__ shf)
{
    int t = blockIdx.x * blockDim.x + threadIdx.x;   // 0..1023 = n*256+c
    if (t < NBR * CHN) {
        const float inv = 1.0f / (float)BL;
        float mean = bnsum[t] * inv;
        float var = bnss[t] * inv - mean * mean;
        float rs = rsqrtf(var + BN_EPS);
        float s = gamma[t] * rs;
        scl[t] = s;
        shf[t] = beta[t] - mean * s;
    }
}

// out = relu(out_pre*scale + shift) + x
__global__ __launch_bounds__(256)
void final_kernel(const ushortT* __restrict__ outpre, const float* __restrict__ x,
                  const float* __restrict__ scl, const float* __restrict__ shf,
                  float* __restrict__ out)
{
    const long long U = (long long)NB_B * CHN * (LEN / 8);   // 8,388,608 units of 8
    for (long long u = (long long)blockIdx.x * blockDim.x + threadIdx.x; u < U;
         u += (long long)gridDim.x * blockDim.x) {
        int l0 = (int)(u & 511) * 8;
        int c  = (int)(u >> 9) & 255;
        int zz = (int)(u >> 17);          // n*16+b
        int n  = zz >> 4;
        size_t base = ((size_t)zz * CHN + c) * LEN + l0;
        ushort8_t op = *(const ushort8_t*)(outpre + base);
        float4 x0 = *(const float4*)(x + base);
        float4 x1 = *(const float4*)(x + base + 4);
        float sc = scl[n * CHN + c];
        float sh = shf[n * CHN + c];
        float xr[8] = {x0.x, x0.y, x0.z, x0.w, x1.x, x1.y, x1.z, x1.w};
        float res[8];
#pragma unroll
        for (int e = 0; e < 8; ++e) {
            float bn = bf2f(op[e]) * sc + sh;
            res[e] = fmaxf(bn, 0.f) + xr[e];
        }
        float4 o0 = {res[0], res[1], res[2], res[3]};
        float4 o1 = {res[4], res[5], res[6], res[7]};
        *(float4*)(out + base) = o0;
        *(float4*)(out + base + 4) = o1;
    }
}

extern "C" void kernel_launch(void* const* d_in, const int* in_sizes, int n_in,
                              void* d_out, int out_size, void* d_ws, size_t ws_size,
                              hipStream_t stream)
{
    const float* x     = (const float*)d_in[0];
    const float* Wq    = (const float*)d_in[1];
    const float* bq    = (const float*)d_in[2];
    const float* Wk    = (const float*)d_in[3];
    const float* bk    = (const float*)d_in[4];
    const float* Wv    = (const float*)d_in[5];
    const float* bv    = (const float*)d_in[6];
    const float* Wo    = (const float*)d_in[7];
    const float* bo    = (const float*)d_in[8];
    const float* gamma = (const float*)d_in[9];
    const float* beta  = (const float*)d_in[10];
    const float* edge  = (const float*)d_in[11];
    const float* bimp  = (const float*)d_in[12];

    char* ws = (char*)d_ws;
    const size_t P_BYTES = (size_t)NBR * BSZ * CHN * LEN * 2;   // 128 MiB (bf16)
    ushortT* outpre = (ushortT*)ws;          // out_pre staging (ws[0:128Mi])
    size_t off = P_BYTES;
    float*    qsum = (float*)(ws + off);    off += 65536;
    unsigned* qmax = (unsigned*)(ws + off); off += 65536;
    float*    ksum = (float*)(ws + off);    off += 65536;
    unsigned* kmax = (unsigned*)(ws + off); off += 65536;
    float*    attn = (float*)(ws + off);    off += 1024;
    float*    bnsum= (float*)(ws + off);    off += 4096;
    float*    bnss = (float*)(ws + off);    off += 4096;
    float*    scl  = (float*)(ws + off);    off += 4096;
    float*    shf  = (float*)(ws + off);    off += 4096;

    // zero the small accumulators (sum=0; max uses encoding where 0 < enc(-inf))
    hipMemsetAsync(ws + P_BYTES, 0, off - P_BYTES, stream);

    // d_out scratch (all dead before final_kernel rewrites d_out):
    //   [0, 128Mi):    v (bf16, [z][c][l]) written by qkv, read by ogemm
    //   [128Mi, +2Mi): Wbf (bf16 weights, fragment order) written by wcvt
    ushortT* vbuf = (ushortT*)d_out;
    ushortT* Wbf  = (ushortT*)((char*)d_out + ((size_t)134217728));
    float*   outf = (float*)d_out;

    wcvt_kernel<<<(4 * (W_EL / 8) + 255) / 256, 256, 0, stream>>>(Wq, Wk, Wv, Wo, Wbf);

    const int NWG = (LEN / LT) * NB_B;   // 4096, %8 == 0
    qkv_kernel<<<NWG, 256, 0, stream>>>(x, Wbf, bv, qsum, qmax, ksum, kmax, vbuf);
    attn_kernel<<<1, 256, 0, stream>>>(qsum, qmax, ksum, kmax, bq, bk, edge, bimp, attn);
    ogemm_kernel<<<NWG, 256, 0, stream>>>(vbuf, Wbf + (size_t)3 * W_EL, attn, bo, bnsum, bnss, outpre);
    bnfin_kernel<<<4, 256, 0, stream>>>(bnsum, bnss, gamma, beta, scl, shf);
    final_kernel<<<8192, 256, 0, stream>>>(outpre, x, scl, shf, outf);
}

// Round 11
// 773.513 us; speedup vs baseline: 1.1600x; 1.1552x over previous
//
#include <hip/hip_runtime.h>
#include <stdint.h>
#include <stddef.h>

// Problem constants (reference: NB=4, B=16, C=256, L=4096)
#define NBR 4
#define BSZ 16
#define CHN 256
#define LEN 4096
#define NB_B 64            // NBR*BSZ
#define BL   65536         // BSZ*LEN
#define BN_EPS 1e-5f
#define W_EL (NBR*CHN*CHN) // 262144 elements per weight tensor
#define LT   128           // l-tile (round-7 value: L2-friendly W reuse)

typedef unsigned short ushortT;
typedef unsigned short ushort4_t __attribute__((ext_vector_type(4)));
typedef unsigned short ushort8_t __attribute__((ext_vector_type(8)));
typedef short bf16x8 __attribute__((ext_vector_type(8)));
typedef float f32x4 __attribute__((ext_vector_type(4)));

__device__ __forceinline__ float bf2f(ushortT u) {
    return __uint_as_float(((unsigned)u) << 16);
}
__device__ __forceinline__ ushortT f2bf(float f) {
    unsigned b = __float_as_uint(f);
    return (ushortT)((b + 0x7FFFu + ((b >> 16) & 1u)) >> 16);
}
// order-preserving float->uint encoding (monotone); memset-0 init is below enc(-inf)
__device__ __forceinline__ unsigned encf(float f) {
    unsigned b = __float_as_uint(f);
    return (b & 0x80000000u) ? ~b : (b | 0x80000000u);
}
__device__ __forceinline__ float decf(unsigned u) {
    unsigned b = (u & 0x80000000u) ? (u ^ 0x80000000u) : ~u;
    return __uint_as_float(b);
}

// LDS swizzle for sX (byte offsets). Rows are 512B (256 c bf16). row in 0..127.
__device__ __forceinline__ int swzX(int row, int cb) {
    return row * 512 + (cb ^ ((row & 7) << 4) ^ (((row >> 3) & 3) << 7));
}

// Stage x-tile [l=128][c=256] into LDS, transposed+converted, swizzled.
// 512 threads: lane -> l (coalesced), 4 threads per l cover 256 c.
__device__ __forceinline__ void stage_x_f32(const float* x, ushortT* sX, int z, int lbase, int tid)
{
    const int ls = tid & 127;
    const int gh = tid >> 7;           // 0..3
    const float* xp = x + (size_t)z * CHN * LEN + lbase + ls;
#pragma unroll
    for (int g = 0; g < 8; ++g) {
        int c0 = (gh * 8 + g) * 8;
        ushort8_t u;
#pragma unroll
        for (int i = 0; i < 8; ++i) u[i] = f2bf(xp[(size_t)(c0 + i) * LEN]);
        *(ushort8_t*)((char*)sX + swzX(ls, c0 * 2)) = u;
    }
}

// Fused-agg staging for ogemm: sX[l][c] = f2bf( sum_j aj[j] * v[j,b,c,l] )
__device__ __forceinline__ void stage_agg(const ushortT* v, ushortT* sX, const float aj[4],
                                          int b_, int lbase, int tid)
{
    const int ls = tid & 127;
    const int gh = tid >> 7;
    const ushortT* vp0 = v + (size_t)(0 * BSZ + b_) * CHN * LEN + lbase + ls;
    const ushortT* vp1 = v + (size_t)(1 * BSZ + b_) * CHN * LEN + lbase + ls;
    const ushortT* vp2 = v + (size_t)(2 * BSZ + b_) * CHN * LEN + lbase + ls;
    const ushortT* vp3 = v + (size_t)(3 * BSZ + b_) * CHN * LEN + lbase + ls;
#pragma unroll
    for (int g = 0; g < 8; ++g) {
        int c0 = (gh * 8 + g) * 8;
        ushort8_t u;
#pragma unroll
        for (int i = 0; i < 8; ++i) {
            size_t o = (size_t)(c0 + i) * LEN;
            float s = aj[0] * bf2f(vp0[o]) + aj[1] * bf2f(vp1[o])
                    + aj[2] * bf2f(vp2[o]) + aj[3] * bf2f(vp3[o]);
            u[i] = f2bf(s);
        }
        *(ushort8_t*)((char*)sX + swzX(ls, c0 * 2)) = u;
    }
}

// One K-chunk (64 c) of MFMA. W B-fragments from global in PRE-PACKED fragment
// order Wb2[ob][cb][lane][8] -> base + lane*16B = coalesced 1KB dwordx4 (L2).
// A = x (M=l) from LDS. acc[mf][nf] row=l col=o. Wave covers 64l x 32o.
__device__ __forceinline__ void mfma_chunk_frag(const ushortT* sX, const ushortT* __restrict__ Wb2,
                                                int otile, f32x4 acc[4][2],
                                                int wr, int wc, int lane, int kb)
{
    const int am = wr * 64 + (lane & 15);
    const int kg = (lane >> 4) * 16;   // byte offset of this lane's k-group (LDS)
#pragma unroll
    for (int s = 0; s < 2; ++s) {
        const int cb = kb * 2 + s;
        bf16x8 a[4], b[2];
#pragma unroll
        for (int nf = 0; nf < 2; ++nf) {
            const int ob = otile * 8 + wc * 2 + nf;
            b[nf] = *(const bf16x8*)(Wb2 + (((size_t)ob * 8 + cb) * 64 + lane) * 8);
        }
#pragma unroll
        for (int mf = 0; mf < 4; ++mf)
            a[mf] = *(const bf16x8*)((const char*)sX + swzX(am + mf * 16, kb * 128 + s * 64 + kg));
#pragma unroll
        for (int mf = 0; mf < 4; ++mf)
#pragma unroll
            for (int nf = 0; nf < 2; ++nf)
                acc[mf][nf] = __builtin_amdgcn_mfma_f32_16x16x32_bf16(a[mf], b[nf], acc[mf][nf], 0, 0, 0);
    }
}

// ---------------------------------------------------------------------------
// QKV fused: stage x-tile (1 barrier), then 6 barrier-free GEMM-tiles.
// 512 threads = 8 waves: (wr: l-half, wc: o-strip). 64KB LDS -> 2 blocks/CU,
// 16 waves/CU (2x round-7 occupancy at identical L2 traffic pattern).
// ---------------------------------------------------------------------------
__global__ __launch_bounds__(512, 4)
void qkv_kernel(const float* __restrict__ x, const ushortT* __restrict__ Wbf,
                const float* __restrict__ bv,
                float* __restrict__ qsum, unsigned* __restrict__ qmax,
                float* __restrict__ ksum, unsigned* __restrict__ kmax,
                ushortT* __restrict__ vbuf)
{
    __shared__ ushortT sX[LT * 256];    // 64 KiB
    const int tid = threadIdx.x;
    const int lane = tid & 63;
    const int wv = tid >> 6;            // 0..7
    const int wr = wv >> 2;             // l-half
    const int wc = wv & 3;              // o-strip
    const int lbase = blockIdx.x * LT;
    const int z = blockIdx.y;
    const int n = z >> 4;

    stage_x_f32(x, sX, z, lbase, tid);
    __syncthreads();                    // the only barrier

    const f32x4 z4 = {0.f, 0.f, 0.f, 0.f};

    for (int w = 0; w < 3; ++w) {
        const ushortT* Wb2 = Wbf + ((size_t)w * NBR + n) * CHN * CHN;
        for (int ot = 0; ot < 2; ++ot) {
            f32x4 acc[4][2];
#pragma unroll
            for (int mf = 0; mf < 4; ++mf)
#pragma unroll
                for (int nf = 0; nf < 2; ++nf) acc[mf][nf] = z4;
#pragma unroll
            for (int kb = 0; kb < 4; ++kb)
                mfma_chunk_frag(sX, Wb2, ot, acc, wr, wc, lane, kb);

            const int obase = ot * 128 + wc * 32;
            if (w < 2) {
                float* rs = (w == 0) ? qsum : ksum;
                unsigned* rm = (w == 0) ? qmax : kmax;
#pragma unroll
                for (int nf = 0; nf < 2; ++nf) {
                    float s = 0.f, m = -3.4e38f;
#pragma unroll
                    for (int mf = 0; mf < 4; ++mf)
#pragma unroll
                        for (int r = 0; r < 4; ++r) {
                            float v = acc[mf][nf][r];
                            s += v; m = fmaxf(m, v);
                        }
                    s += __shfl_xor(s, 16); s += __shfl_xor(s, 32);
                    m = fmaxf(m, __shfl_xor(m, 16)); m = fmaxf(m, __shfl_xor(m, 32));
                    if (lane < 16) {
                        int o = obase + nf * 16 + lane;
                        atomicAdd(&rs[z * CHN + o], s);
                        atomicMax(&rm[z * CHN + o], encf(m));
                    }
                }
            } else {
#pragma unroll
                for (int nf = 0; nf < 2; ++nf) {
                    int o = obase + nf * 16 + (lane & 15);
                    float bvv = bv[n * CHN + o];
#pragma unroll
                    for (int mf = 0; mf < 4; ++mf) {
                        int l = lbase + wr * 64 + mf * 16 + ((lane >> 4) << 2);
                        ushort4_t u;
#pragma unroll
                        for (int r = 0; r < 4; ++r) u[r] = f2bf(acc[mf][nf][r] + bvv);
                        *(ushort4_t*)(vbuf + (size_t)(z * CHN + o) * LEN + l) = u;
                    }
                }
            }
        }
    }
}

// ---------------------------------------------------------------------------
// O GEMM with FUSED aggregation: stage combines 4 v-slices with attn weights
// in-register, then barrier-free Wo GEMM -> out_pre[z][c][l] + BN stats.
// Same 512-thread 8-wave shape.
// ---------------------------------------------------------------------------
__global__ __launch_bounds__(512, 4)
void ogemm_kernel(const ushortT* __restrict__ v, const ushortT* __restrict__ Wbo,
                  const float* __restrict__ attn, const float* __restrict__ bo_,
                  float* __restrict__ bnsum, float* __restrict__ bnss,
                  ushortT* __restrict__ outpre)
{
    __shared__ ushortT sX[LT * 256];
    const int tid = threadIdx.x;
    const int lane = tid & 63;
    const int wv = tid >> 6;
    const int wr = wv >> 2;
    const int wc = wv & 3;
    const int lbase = blockIdx.x * LT;
    const int z = blockIdx.y;
    const int n = z >> 4;          // output branch i
    const int b_ = z & 15;
    const ushortT* Wb2 = Wbo + (size_t)n * CHN * CHN;

    float aj[4];
#pragma unroll
    for (int j = 0; j < 4; ++j) aj[j] = attn[(n * 4 + j) * BSZ + b_];

    stage_agg(v, sX, aj, b_, lbase, tid);
    __syncthreads();                    // the only barrier

    const f32x4 z4 = {0.f, 0.f, 0.f, 0.f};
    for (int ot = 0; ot < 2; ++ot) {
        f32x4 acc[4][2];
#pragma unroll
        for (int mf = 0; mf < 4; ++mf)
#pragma unroll
            for (int nf = 0; nf < 2; ++nf) acc[mf][nf] = z4;
#pragma unroll
        for (int kb = 0; kb < 4; ++kb)
            mfma_chunk_frag(sX, Wb2, ot, acc, wr, wc, lane, kb);

        const int obase = ot * 128 + wc * 32;
#pragma unroll
        for (int nf = 0; nf < 2; ++nf) {
            int o = obase + nf * 16 + (lane & 15);
            float bb = bo_[n * CHN + o];
            float s = 0.f, q2 = 0.f;
#pragma unroll
            for (int mf = 0; mf < 4; ++mf) {
                int l = lbase + wr * 64 + mf * 16 + ((lane >> 4) << 2);
                ushort4_t u;
#pragma unroll
                for (int r = 0; r < 4; ++r) {
                    float vv = acc[mf][nf][r] + bb;
                    u[r] = f2bf(vv);
                    s += vv; q2 += vv * vv;
                }
                *(ushort4_t*)(outpre + (size_t)(z * CHN + o) * LEN + l) = u;
            }
            s += __shfl_xor(s, 16); s += __shfl_xor(s, 32);
            q2 += __shfl_xor(q2, 16); q2 += __shfl_xor(q2, 32);
            if (lane < 16) {
                atomicAdd(&bnsum[n * CHN + o], s);
                atomicAdd(&bnss[n * CHN + o], q2);
            }
        }
    }
}

// convert all 4 weight tensors fp32 -> bf16 in MFMA-FRAGMENT order:
// Wbf[w][n][ob][cb][lane][8] with o = ob*16 + (lane&15), c = cb*32 + (lane>>4)*8 + j
__global__ void wcvt_kernel(const float* __restrict__ Wq, const float* __restrict__ Wk,
                            const float* __restrict__ Wv, const float* __restrict__ Wo,
                            ushortT* __restrict__ Wbf)
{
    int t = blockIdx.x * 256 + threadIdx.x;    // one thread per 8-elem fragment slice
    if (t < 4 * (W_EL / 8)) {
        const float* srcs[4] = {Wq, Wk, Wv, Wo};
        int w    = t >> 15;          // W_EL/8 = 32768 per tensor
        int r    = t & 32767;
        int lane = r & 63;
        int cb   = (r >> 6) & 7;
        int ob   = (r >> 9) & 15;
        int n    = r >> 13;
        const float* src = srcs[w] + (size_t)n * CHN * CHN;
        int o = ob * 16 + (lane & 15);
        int c = cb * 32 + (lane >> 4) * 8;
        float4 f0 = *(const float4*)(src + (size_t)o * CHN + c);
        float4 f1 = *(const float4*)(src + (size_t)o * CHN + c + 4);
        ushort8_t u = {f2bf(f0.x), f2bf(f0.y), f2bf(f0.z), f2bf(f0.w),
                       f2bf(f1.x), f2bf(f1.y), f2bf(f1.z), f2bf(f1.w)};
        *(ushort8_t*)(Wbf + ((size_t)w * NBR + n) * CHN * CHN
                          + (((size_t)ob * 8 + cb) * 64 + lane) * 8) = u;
    }
}

// ---------------------------------------------------------------------------
// attention coefficients: scores[i,j,b] = (sum_c sq*sk) * edge_w[i,j] / 64
// attn[i,j,b] = softmax_j(scores) * softmax(branch_imp)[j]
// sq = qsum/L + dec(qmax) + 2*bq  (mean+max, bias shifts both by bq)
// ---------------------------------------------------------------------------
__global__ void attn_kernel(const float* __restrict__ qsum, const unsigned* __restrict__ qmax,
                            const float* __restrict__ ksum, const unsigned* __restrict__ kmax,
                            const float* __restrict__ bq, const float* __restrict__ bk,
                            const float* __restrict__ edge, const float* __restrict__ bimp,
                            float* __restrict__ attn)
{
    __shared__ float sc[NBR][NBR][BSZ];
    int tid = threadIdx.x;           // 256 threads == 4*4*16
    int i = tid >> 6, j = (tid >> 4) & 3, b = tid & 15;
    float s = 0.f;
    const float invL = 1.0f / (float)LEN;
    for (int c = 0; c < CHN; ++c) {
        int qi = (i * BSZ + b) * CHN + c;
        int ki = (j * BSZ + b) * CHN + c;
        float sq = qsum[qi] * invL + decf(qmax[qi]) + 2.f * bq[i * CHN + c];
        float sk = ksum[ki] * invL + decf(kmax[ki]) + 2.f * bk[j * CHN + c];
        s += sq * sk;
    }
    sc[i][j][b] = s * edge[i * 4 + j] * (1.0f / 64.0f);
    __syncthreads();
    if (tid < 64) {
        int ii = tid >> 4, bb = tid & 15;
        float m = -3.4e38f;
        for (int jj = 0; jj < 4; ++jj) m = fmaxf(m, sc[ii][jj][bb]);
        float e[4]; float sum = 0.f;
        for (int jj = 0; jj < 4; ++jj) { e[jj] = __expf(sc[ii][jj][bb] - m); sum += e[jj]; }
        float bm = fmaxf(fmaxf(bimp[0], bimp[1]), fmaxf(bimp[2], bimp[3]));
        float be[4]; float bs = 0.f;
        for (int jj = 0; jj < 4; ++jj) { be[jj] = __expf(bimp[jj] - bm); bs += be[jj]; }
        for (int jj = 0; jj < 4; ++jj)
            attn[(ii * 4 + jj) * BSZ + bb] = (e[jj] / sum) * (be[jj] / bs);
    }
}

// finalize BN affine: scale = gamma*rsqrt(var+eps), shift = beta - mean*scale
__global__ void bnfin_kernel(const float* __restrict__ bnsum, const float* __restrict__ bnss,
                             const float* __restrict__ gamma, const float* __restrict__ beta,
                             float* __restrict__ scl, float* __restrict__ shf)
{
    int t = blockIdx.x * blockDim.x + threadIdx.x;   // 0..1023 = n*256+c
    if (t < NBR * CHN) {
        const float inv = 1.0f / (float)BL;
        float mean = bnsum[t] * inv;
        float var = bnss[t] * inv - mean * mean;
        float rs = rsqrtf(var + BN_EPS);
        float s = gamma[t] * rs;
        scl[t] = s;
        shf[t] = beta[t] - mean * s;
    }
}

// out = relu(out_pre*scale + shift) + x
__global__ __launch_bounds__(256)
void final_kernel(const ushortT* __restrict__ outpre, const float* __restrict__ x,
                  const float* __restrict__ scl, const float* __restrict__ shf,
                  float* __restrict__ out)
{
    const long long U = (long long)NB_B * CHN * (LEN / 8);   // 8,388,608 units of 8
    for (long long u = (long long)blockIdx.x * blockDim.x + threadIdx.x; u < U;
         u += (long long)gridDim.x * blockDim.x) {
        int l0 = (int)(u & 511) * 8;
        int c  = (int)(u >> 9) & 255;
        int zz = (int)(u >> 17);          // n*16+b
        int n  = zz >> 4;
        size_t base = ((size_t)zz * CHN + c) * LEN + l0;
        ushort8_t op = *(const ushort8_t*)(outpre + base);
        float4 x0 = *(const float4*)(x + base);
        float4 x1 = *(const float4*)(x + base + 4);
        float sc = scl[n * CHN + c];
        float sh = shf[n * CHN + c];
        float xr[8] = {x0.x, x0.y, x0.z, x0.w, x1.x, x1.y, x1.z, x1.w};
        float res[8];
#pragma unroll
        for (int e = 0; e < 8; ++e) {
            float bn = bf2f(op[e]) * sc + sh;
            res[e] = fmaxf(bn, 0.f) + xr[e];
        }
        float4 o0 = {res[0], res[1], res[2], res[3]};
        float4 o1 = {res[4], res[5], res[6], res[7]};
        *(float4*)(out + base) = o0;
        *(float4*)(out + base + 4) = o1;
    }
}

extern "C" void kernel_launch(void* const* d_in, const int* in_sizes, int n_in,
                              void* d_out, int out_size, void* d_ws, size_t ws_size,
                              hipStream_t stream)
{
    const float* x     = (const float*)d_in[0];
    const float* Wq    = (const float*)d_in[1];
    const float* bq    = (const float*)d_in[2];
    const float* Wk    = (const float*)d_in[3];
    const float* bk    = (const float*)d_in[4];
    const float* Wv    = (const float*)d_in[5];
    const float* bv    = (const float*)d_in[6];
    const float* Wo    = (const float*)d_in[7];
    const float* bo    = (const float*)d_in[8];
    const float* gamma = (const float*)d_in[9];
    const float* beta  = (const float*)d_in[10];
    const float* edge  = (const float*)d_in[11];
    const float* bimp  = (const float*)d_in[12];

    char* ws = (char*)d_ws;
    const size_t P_BYTES = (size_t)NBR * BSZ * CHN * LEN * 2;   // 128 MiB (bf16)
    ushortT* outpre = (ushortT*)ws;          // out_pre staging (ws[0:128Mi])
    size_t off = P_BYTES;
    float*    qsum = (float*)(ws + off);    off += 65536;
    unsigned* qmax = (unsigned*)(ws + off); off += 65536;
    float*    ksum = (float*)(ws + off);    off += 65536;
    unsigned* kmax = (unsigned*)(ws + off); off += 65536;
    float*    attn = (float*)(ws + off);    off += 1024;
    float*    bnsum= (float*)(ws + off);    off += 4096;
    float*    bnss = (float*)(ws + off);    off += 4096;
    float*    scl  = (float*)(ws + off);    off += 4096;
    float*    shf  = (float*)(ws + off);    off += 4096;

    // zero the small accumulators (sum=0; max uses encoding where 0 < enc(-inf))
    hipMemsetAsync(ws + P_BYTES, 0, off - P_BYTES, stream);

    // d_out scratch (all dead before final_kernel rewrites d_out):
    //   [0, 128Mi):    v (bf16, [z][c][l]) written by qkv, read by ogemm
    //   [128Mi, +2Mi): Wbf (bf16 weights, fragment order) written by wcvt
    ushortT* vbuf = (ushortT*)d_out;
    ushortT* Wbf  = (ushortT*)((char*)d_out + ((size_t)134217728));
    float*   outf = (float*)d_out;

    wcvt_kernel<<<(4 * (W_EL / 8) + 255) / 256, 256, 0, stream>>>(Wq, Wk, Wv, Wo, Wbf);

    dim3 gq(LEN / LT, NB_B);   // (32, 64)
    qkv_kernel<<<gq, 512, 0, stream>>>(x, Wbf, bv, qsum, qmax, ksum, kmax, vbuf);
    attn_kernel<<<1, 256, 0, stream>>>(qsum, qmax, ksum, kmax, bq, bk, edge, bimp, attn);
    ogemm_kernel<<<gq, 512, 0, stream>>>(vbuf, Wbf + (size_t)3 * W_EL, attn, bo, bnsum, bnss, outpre);
    bnfin_kernel<<<4, 256, 0, stream>>>(bnsum, bnss, gamma, beta, scl, shf);
    final_kernel<<<8192, 256, 0, stream>>>(outpre, x, scl, shf, outf);
}

// Round 12
// 599.671 us; speedup vs baseline: 1.4963x; 1.2899x over previous
//
#include <hip/hip_runtime.h>
#include <stdint.h>
#include <stddef.h>

// Problem constants (reference: NB=4, B=16, C=256, L=4096)
#define NBR 4
#define BSZ 16
#define CHN 256
#define LEN 4096
#define NB_B 64            // NBR*BSZ
#define BL   65536         // BSZ*LEN
#define BN_EPS 1e-5f
#define W_EL (NBR*CHN*CHN) // 262144 elements per weight tensor
#define LT   128           // l-tile (round-7 value: the only L2-clean shape)

typedef unsigned short ushortT;
typedef unsigned short ushort4_t __attribute__((ext_vector_type(4)));
typedef unsigned short ushort8_t __attribute__((ext_vector_type(8)));
typedef short bf16x8 __attribute__((ext_vector_type(8)));
typedef float f32x4 __attribute__((ext_vector_type(4)));

__device__ __forceinline__ float bf2f(ushortT u) {
    return __uint_as_float(((unsigned)u) << 16);
}
__device__ __forceinline__ ushortT f2bf(float f) {
    unsigned b = __float_as_uint(f);
    return (ushortT)((b + 0x7FFFu + ((b >> 16) & 1u)) >> 16);
}
// order-preserving float->uint encoding (monotone); memset-0 init is below enc(-inf)
__device__ __forceinline__ unsigned encf(float f) {
    unsigned b = __float_as_uint(f);
    return (b & 0x80000000u) ? ~b : (b | 0x80000000u);
}
__device__ __forceinline__ float decf(unsigned u) {
    unsigned b = (u & 0x80000000u) ? (u ^ 0x80000000u) : ~u;
    return __uint_as_float(b);
}

// LDS swizzle for sX (byte offsets). Rows are 512B (256 c bf16). row in 0..127.
__device__ __forceinline__ int swzX(int row, int cb) {
    return row * 512 + (cb ^ ((row & 7) << 4) ^ (((row >> 3) & 3) << 7));
}

// Stage x-tile [l=128][c=256] into LDS, transposed+converted, swizzled.
// Loads are coalesced per wave-instruction (lane -> l).
__device__ __forceinline__ void stage_x_f32(const float* x, ushortT* sX, int z, int lbase, int tid)
{
    const int ls = tid & 127;
    const int gh = tid >> 7;
    const float* xp = x + (size_t)z * CHN * LEN + lbase + ls;
#pragma unroll
    for (int g = 0; g < 16; ++g) {
        int c0 = (gh * 16 + g) * 8;
        ushort8_t u;
#pragma unroll
        for (int i = 0; i < 8; ++i) u[i] = f2bf(xp[(size_t)(c0 + i) * LEN]);
        *(ushort8_t*)((char*)sX + swzX(ls, c0 * 2)) = u;
    }
}

// Fused-agg staging for ogemm: sX[l][c] = f2bf( sum_j aj[j] * v[j,b,c,l] )
// v layout [z][c][l]; reads coalesced (lane -> l), 4 slices summed in-reg.
__device__ __forceinline__ void stage_agg(const ushortT* v, ushortT* sX, const float aj[4],
                                          int b_, int lbase, int tid)
{
    const int ls = tid & 127;
    const int gh = tid >> 7;
    const ushortT* vp0 = v + (size_t)(0 * BSZ + b_) * CHN * LEN + lbase + ls;
    const ushortT* vp1 = v + (size_t)(1 * BSZ + b_) * CHN * LEN + lbase + ls;
    const ushortT* vp2 = v + (size_t)(2 * BSZ + b_) * CHN * LEN + lbase + ls;
    const ushortT* vp3 = v + (size_t)(3 * BSZ + b_) * CHN * LEN + lbase + ls;
#pragma unroll
    for (int g = 0; g < 16; ++g) {
        int c0 = (gh * 16 + g) * 8;
        ushort8_t u;
#pragma unroll
        for (int i = 0; i < 8; ++i) {
            size_t o = (size_t)(c0 + i) * LEN;
            float s = aj[0] * bf2f(vp0[o]) + aj[1] * bf2f(vp1[o])
                    + aj[2] * bf2f(vp2[o]) + aj[3] * bf2f(vp3[o]);
            u[i] = f2bf(s);
        }
        *(ushort8_t*)((char*)sX + swzX(ls, c0 * 2)) = u;
    }
}

// W B-fragment block for one K-chunk: b[s][nf], each 16B/lane, PRE-PACKED
// fragment order Wb2[ob][cb][lane][8] -> coalesced 1KB dwordx4 from L2.
__device__ __forceinline__ void load_wfrag(const ushortT* __restrict__ Wb2, int otile,
                                           int wc, int lane, int kb, bf16x8 b[2][4])
{
#pragma unroll
    for (int s = 0; s < 2; ++s) {
        const int cb = kb * 2 + s;
#pragma unroll
        for (int nf = 0; nf < 4; ++nf) {
            const int ob = otile * 8 + wc * 4 + nf;
            b[s][nf] = *(const bf16x8*)(Wb2 + (((size_t)ob * 8 + cb) * 64 + lane) * 8);
        }
    }
}

// Apply one K-chunk (64 c) of MFMA with pre-loaded W regs.
// A = x (M=l) from LDS. acc[mf][nf] row=l col=o. Wave covers 64l x 64o.
__device__ __forceinline__ void mfma_apply(const ushortT* sX, f32x4 acc[4][4],
                                           int wr, int lane, int kb, const bf16x8 b[2][4])
{
    const int am = wr * 64 + (lane & 15);
    const int kg = (lane >> 4) * 16;   // byte offset of this lane's k-group (LDS)
#pragma unroll
    for (int s = 0; s < 2; ++s) {
        bf16x8 a[4];
#pragma unroll
        for (int mf = 0; mf < 4; ++mf)
            a[mf] = *(const bf16x8*)((const char*)sX + swzX(am + mf * 16, kb * 128 + s * 64 + kg));
#pragma unroll
        for (int mf = 0; mf < 4; ++mf)
#pragma unroll
            for (int nf = 0; nf < 4; ++nf)
                acc[mf][nf] = __builtin_amdgcn_mfma_f32_16x16x32_bf16(a[mf], b[s][nf], acc[mf][nf], 0, 0, 0);
    }
}

// ---------------------------------------------------------------------------
// QKV fused: stage x-tile once (ONE barrier), then 6 barrier-free GEMM-tiles.
// W fragments register-prefetched one K-chunk ahead: chunk k+1's L2 loads
// overlap chunk k's 32 MFMAs (the round-7 latency chain, pipelined).
// ---------------------------------------------------------------------------
__global__ __launch_bounds__(256, 2)
void qkv_kernel(const float* __restrict__ x, const ushortT* __restrict__ Wbf,
                const float* __restrict__ bv,
                float* __restrict__ qsum, unsigned* __restrict__ qmax,
                float* __restrict__ ksum, unsigned* __restrict__ kmax,
                ushortT* __restrict__ vbuf)
{
    __shared__ ushortT sX[LT * 256];    // 64 KiB (only LDS)
    const int tid = threadIdx.x;
    const int lane = tid & 63;
    const int wv = tid >> 6;
    const int wr = wv >> 1, wc = wv & 1;
    const int lbase = blockIdx.x * LT;
    const int z = blockIdx.y;
    const int n = z >> 4;

    stage_x_f32(x, sX, z, lbase, tid);

    bf16x8 bcur[2][4], bnxt[2][4];
    load_wfrag(Wbf + (size_t)n * CHN * CHN, 0, wc, lane, 0, bcur);   // chunk 0

    __syncthreads();                    // the only barrier

    const f32x4 z4 = {0.f, 0.f, 0.f, 0.f};

    for (int w = 0; w < 3; ++w) {
        for (int ot = 0; ot < 2; ++ot) {
            f32x4 acc[4][4];
#pragma unroll
            for (int mf = 0; mf < 4; ++mf)
#pragma unroll
                for (int nf = 0; nf < 4; ++nf) acc[mf][nf] = z4;

#pragma unroll
            for (int kb = 0; kb < 4; ++kb) {
                int cidx = (w * 2 + ot) * 4 + kb + 1;    // next chunk 1..24
                if (cidx < 24) {
                    int nw = cidx >> 3, not_ = (cidx >> 2) & 1, nkb = cidx & 3;
                    load_wfrag(Wbf + ((size_t)nw * NBR + n) * CHN * CHN,
                               not_, wc, lane, nkb, bnxt);
                }
                mfma_apply(sX, acc, wr, lane, kb, bcur);
#pragma unroll
                for (int s = 0; s < 2; ++s)
#pragma unroll
                    for (int nf = 0; nf < 4; ++nf) bcur[s][nf] = bnxt[s][nf];
            }

            const int obase = ot * 128;
            if (w < 2) {
                float* rs = (w == 0) ? qsum : ksum;
                unsigned* rm = (w == 0) ? qmax : kmax;
#pragma unroll
                for (int nf = 0; nf < 4; ++nf) {
                    float s = 0.f, m = -3.4e38f;
#pragma unroll
                    for (int mf = 0; mf < 4; ++mf)
#pragma unroll
                        for (int r = 0; r < 4; ++r) {
                            float v = acc[mf][nf][r];
                            s += v; m = fmaxf(m, v);
                        }
                    s += __shfl_xor(s, 16); s += __shfl_xor(s, 32);
                    m = fmaxf(m, __shfl_xor(m, 16)); m = fmaxf(m, __shfl_xor(m, 32));
                    if (lane < 16) {
                        int o = obase + wc * 64 + nf * 16 + lane;
                        atomicAdd(&rs[z * CHN + o], s);
                        atomicMax(&rm[z * CHN + o], encf(m));
                    }
                }
            } else {
#pragma unroll
                for (int nf = 0; nf < 4; ++nf) {
                    int o = obase + wc * 64 + nf * 16 + (lane & 15);
                    float bvv = bv[n * CHN + o];
#pragma unroll
                    for (int mf = 0; mf < 4; ++mf) {
                        int l = lbase + wr * 64 + mf * 16 + ((lane >> 4) << 2);
                        ushort4_t u;
#pragma unroll
                        for (int r = 0; r < 4; ++r) u[r] = f2bf(acc[mf][nf][r] + bvv);
                        *(ushort4_t*)(vbuf + (size_t)(z * CHN + o) * LEN + l) = u;
                    }
                }
            }
        }
    }
}

// ---------------------------------------------------------------------------
// O GEMM with FUSED aggregation: stage combines 4 v-slices with attn weights
// in-register (agg kernel + its 256MB round-trip eliminated), then
// barrier-free Wo GEMM with the same register W-prefetch.
// ---------------------------------------------------------------------------
__global__ __launch_bounds__(256, 2)
void ogemm_kernel(const ushortT* __restrict__ v, const ushortT* __restrict__ Wbo,
                  const float* __restrict__ attn, const float* __restrict__ bo_,
                  float* __restrict__ bnsum, float* __restrict__ bnss,
                  ushortT* __restrict__ outpre)
{
    __shared__ ushortT sX[LT * 256];
    const int tid = threadIdx.x;
    const int lane = tid & 63;
    const int wv = tid >> 6;
    const int wr = wv >> 1, wc = wv & 1;
    const int lbase = blockIdx.x * LT;
    const int z = blockIdx.y;
    const int n = z >> 4;          // output branch i
    const int b_ = z & 15;
    const ushortT* Wb2 = Wbo + (size_t)n * CHN * CHN;

    float aj[4];
#pragma unroll
    for (int j = 0; j < 4; ++j) aj[j] = attn[(n * 4 + j) * BSZ + b_];

    stage_agg(v, sX, aj, b_, lbase, tid);

    bf16x8 bcur[2][4], bnxt[2][4];
    load_wfrag(Wb2, 0, wc, lane, 0, bcur);

    __syncthreads();                    // the only barrier

    const f32x4 z4 = {0.f, 0.f, 0.f, 0.f};
    for (int ot = 0; ot < 2; ++ot) {
        f32x4 acc[4][4];
#pragma unroll
        for (int mf = 0; mf < 4; ++mf)
#pragma unroll
            for (int nf = 0; nf < 4; ++nf) acc[mf][nf] = z4;

#pragma unroll
        for (int kb = 0; kb < 4; ++kb) {
            int cidx = ot * 4 + kb + 1;   // next chunk 1..8
            if (cidx < 8)
                load_wfrag(Wb2, (cidx >> 2) & 1, wc, lane, cidx & 3, bnxt);
            mfma_apply(sX, acc, wr, lane, kb, bcur);
#pragma unroll
            for (int s = 0; s < 2; ++s)
#pragma unroll
                for (int nf = 0; nf < 4; ++nf) bcur[s][nf] = bnxt[s][nf];
        }

        const int obase = ot * 128;
#pragma unroll
        for (int nf = 0; nf < 4; ++nf) {
            int o = obase + wc * 64 + nf * 16 + (lane & 15);
            float bb = bo_[n * CHN + o];
            float s = 0.f, q2 = 0.f;
#pragma unroll
            for (int mf = 0; mf < 4; ++mf) {
                int l = lbase + wr * 64 + mf * 16 + ((lane >> 4) << 2);
                ushort4_t u;
#pragma unroll
                for (int r = 0; r < 4; ++r) {
                    float vv = acc[mf][nf][r] + bb;
                    u[r] = f2bf(vv);
                    s += vv; q2 += vv * vv;
                }
                *(ushort4_t*)(outpre + (size_t)(z * CHN + o) * LEN + l) = u;
            }
            s += __shfl_xor(s, 16); s += __shfl_xor(s, 32);
            q2 += __shfl_xor(q2, 16); q2 += __shfl_xor(q2, 32);
            if (lane < 16) {
                atomicAdd(&bnsum[n * CHN + o], s);
                atomicAdd(&bnss[n * CHN + o], q2);
            }
        }
    }
}

// convert all 4 weight tensors fp32 -> bf16 in MFMA-FRAGMENT order:
// Wbf[w][n][ob][cb][lane][8] with o = ob*16 + (lane&15), c = cb*32 + (lane>>4)*8 + j
__global__ void wcvt_kernel(const float* __restrict__ Wq, const float* __restrict__ Wk,
                            const float* __restrict__ Wv, const float* __restrict__ Wo,
                            ushortT* __restrict__ Wbf)
{
    int t = blockIdx.x * 256 + threadIdx.x;    // one thread per 8-elem fragment slice
    if (t < 4 * (W_EL / 8)) {
        const float* srcs[4] = {Wq, Wk, Wv, Wo};
        int w    = t >> 15;          // W_EL/8 = 32768 per tensor
        int r    = t & 32767;
        int lane = r & 63;
        int cb   = (r >> 6) & 7;
        int ob   = (r >> 9) & 15;
        int n    = r >> 13;
        const float* src = srcs[w] + (size_t)n * CHN * CHN;
        int o = ob * 16 + (lane & 15);
        int c = cb * 32 + (lane >> 4) * 8;
        float4 f0 = *(const float4*)(src + (size_t)o * CHN + c);
        float4 f1 = *(const float4*)(src + (size_t)o * CHN + c + 4);
        ushort8_t u = {f2bf(f0.x), f2bf(f0.y), f2bf(f0.z), f2bf(f0.w),
                       f2bf(f1.x), f2bf(f1.y), f2bf(f1.z), f2bf(f1.w)};
        *(ushort8_t*)(Wbf + ((size_t)w * NBR + n) * CHN * CHN
                          + (((size_t)ob * 8 + cb) * 64 + lane) * 8) = u;
    }
}

// ---------------------------------------------------------------------------
// attention coefficients: scores[i,j,b] = (sum_c sq*sk) * edge_w[i,j] / 64
// attn[i,j,b] = softmax_j(scores) * softmax(branch_imp)[j]
// sq = qsum/L + dec(qmax) + 2*bq  (mean+max, bias shifts both by bq)
// ---------------------------------------------------------------------------
__global__ void attn_kernel(const float* __restrict__ qsum, const unsigned* __restrict__ qmax,
                            const float* __restrict__ ksum, const unsigned* __restrict__ kmax,
                            const float* __restrict__ bq, const float* __restrict__ bk,
                            const float* __restrict__ edge, const float* __restrict__ bimp,
                            float* __restrict__ attn)
{
    __shared__ float sc[NBR][NBR][BSZ];
    int tid = threadIdx.x;           // 256 threads == 4*4*16
    int i = tid >> 6, j = (tid >> 4) & 3, b = tid & 15;
    float s = 0.f;
    const float invL = 1.0f / (float)LEN;
    for (int c = 0; c < CHN; ++c) {
        int qi = (i * BSZ + b) * CHN + c;
        int ki = (j * BSZ + b) * CHN + c;
        float sq = qsum[qi] * invL + decf(qmax[qi]) + 2.f * bq[i * CHN + c];
        float sk = ksum[ki] * invL + decf(kmax[ki]) + 2.f * bk[j * CHN + c];
        s += sq * sk;
    }
    sc[i][j][b] = s * edge[i * 4 + j] * (1.0f / 64.0f);
    __syncthreads();
    if (tid < 64) {
        int ii = tid >> 4, bb = tid & 15;
        float m = -3.4e38f;
        for (int jj = 0; jj < 4; ++jj) m = fmaxf(m, sc[ii][jj][bb]);
        float e[4]; float sum = 0.f;
        for (int jj = 0; jj < 4; ++jj) { e[jj] = __expf(sc[ii][jj][bb] - m); sum += e[jj]; }
        float bm = fmaxf(fmaxf(bimp[0], bimp[1]), fmaxf(bimp[2], bimp[3]));
        float be[4]; float bs = 0.f;
        for (int jj = 0; jj < 4; ++jj) { be[jj] = __expf(bimp[jj] - bm); bs += be[jj]; }
        for (int jj = 0; jj < 4; ++jj)
            attn[(ii * 4 + jj) * BSZ + bb] = (e[jj] / sum) * (be[jj] / bs);
    }
}

// finalize BN affine: scale = gamma*rsqrt(var+eps), shift = beta - mean*scale
__global__ void bnfin_kernel(const float* __restrict__ bnsum, const float* __restrict__ bnss,
                             const float* __restrict__ gamma, const float* __restrict__ beta,
                             float* __restrict__ scl, float* __restrict__ shf)
{
    int t = blockIdx.x * blockDim.x + threadIdx.x;   // 0..1023 = n*256+c
    if (t < NBR * CHN) {
        const float inv = 1.0f / (float)BL;
        float mean = bnsum[t] * inv;
        float var = bnss[t] * inv - mean * mean;
        float rs = rsqrtf(var + BN_EPS);
        float s = gamma[t] * rs;
        scl[t] = s;
        shf[t] = beta[t] - mean * s;
    }
}

// out = relu(out_pre*scale + shift) + x
__global__ __launch_bounds__(256)
void final_kernel(const ushortT* __restrict__ outpre, const float* __restrict__ x,
                  const float* __restrict__ scl, const float* __restrict__ shf,
                  float* __restrict__ out)
{
    const long long U = (long long)NB_B * CHN * (LEN / 8);   // 8,388,608 units of 8
    for (long long u = (long long)blockIdx.x * blockDim.x + threadIdx.x; u < U;
         u += (long long)gridDim.x * blockDim.x) {
        int l0 = (int)(u & 511) * 8;
        int c  = (int)(u >> 9) & 255;
        int zz = (int)(u >> 17);          // n*16+b
        int n  = zz >> 4;
        size_t base = ((size_t)zz * CHN + c) * LEN + l0;
        ushort8_t op = *(const ushort8_t*)(outpre + base);
        float4 x0 = *(const float4*)(x + base);
        float4 x1 = *(const float4*)(x + base + 4);
        float sc = scl[n * CHN + c];
        float sh = shf[n * CHN + c];
        float xr[8] = {x0.x, x0.y, x0.z, x0.w, x1.x, x1.y, x1.z, x1.w};
        float res[8];
#pragma unroll
        for (int e = 0; e < 8; ++e) {
            float bn = bf2f(op[e]) * sc + sh;
            res[e] = fmaxf(bn, 0.f) + xr[e];
        }
        float4 o0 = {res[0], res[1], res[2], res[3]};
        float4 o1 = {res[4], res[5], res[6], res[7]};
        *(float4*)(out + base) = o0;
        *(float4*)(out + base + 4) = o1;
    }
}

extern "C" void kernel_launch(void* const* d_in, const int* in_sizes, int n_in,
                              void* d_out, int out_size, void* d_ws, size_t ws_size,
                              hipStream_t stream)
{
    const float* x     = (const float*)d_in[0];
    const float* Wq    = (const float*)d_in[1];
    const float* bq    = (const float*)d_in[2];
    const float* Wk    = (const float*)d_in[3];
    const float* bk    = (const float*)d_in[4];
    const float* Wv    = (const float*)d_in[5];
    const float* bv    = (const float*)d_in[6];
    const float* Wo    = (const float*)d_in[7];
    const float* bo    = (const float*)d_in[8];
    const float* gamma = (const float*)d_in[9];
    const float* beta  = (const float*)d_in[10];
    const float* edge  = (const float*)d_in[11];
    const float* bimp  = (const float*)d_in[12];

    char* ws = (char*)d_ws;
    const size_t P_BYTES = (size_t)NBR * BSZ * CHN * LEN * 2;   // 128 MiB (bf16)
    ushortT* outpre = (ushortT*)ws;          // out_pre staging (ws[0:128Mi])
    size_t off = P_BYTES;
    float*    qsum = (float*)(ws + off);    off += 65536;
    unsigned* qmax = (unsigned*)(ws + off); off += 65536;
    float*    ksum = (float*)(ws + off);    off += 65536;
    unsigned* kmax = (unsigned*)(ws + off); off += 65536;
    float*    attn = (float*)(ws + off);    off += 1024;
    float*    bnsum= (float*)(ws + off);    off += 4096;
    float*    bnss = (float*)(ws + off);    off += 4096;
    float*    scl  = (float*)(ws + off);    off += 4096;
    float*    shf  = (float*)(ws + off);    off += 4096;

    // zero the small accumulators (sum=0; max uses encoding where 0 < enc(-inf))
    hipMemsetAsync(ws + P_BYTES, 0, off - P_BYTES, stream);

    // d_out scratch (all dead before final_kernel rewrites d_out):
    //   [0, 128Mi):    v (bf16, [z][c][l]) written by qkv, read by ogemm
    //   [128Mi, +2Mi): Wbf (bf16 weights, fragment order) written by wcvt
    ushortT* vbuf = (ushortT*)d_out;
    ushortT* Wbf  = (ushortT*)((char*)d_out + ((size_t)134217728));
    float*   outf = (float*)d_out;

    wcvt_kernel<<<(4 * (W_EL / 8) + 255) / 256, 256, 0, stream>>>(Wq, Wk, Wv, Wo, Wbf);

    dim3 gq(LEN / LT, NB_B);   // (32, 64)
    qkv_kernel<<<gq, 256, 0, stream>>>(x, Wbf, bv, qsum, qmax, ksum, kmax, vbuf);
    attn_kernel<<<1, 256, 0, stream>>>(qsum, qmax, ksum, kmax, bq, bk, edge, bimp, attn);
    ogemm_kernel<<<gq, 256, 0, stream>>>(vbuf, Wbf + (size_t)3 * W_EL, attn, bo, bnsum, bnss, outpre);
    bnfin_kernel<<<4, 256, 0, stream>>>(bnsum, bnss, gamma, beta, scl, shf);
    final_kernel<<<8192, 256, 0, stream>>>(outpre, x, scl, shf, outf);
}

// Round 13
// 516.543 us; speedup vs baseline: 1.7371x; 1.1609x over previous
//
#include <hip/hip_runtime.h>
#include <stdint.h>
#include <stddef.h>

// Problem constants (reference: NB=4, B=16, C=256, L=4096)
#define NBR 4
#define BSZ 16
#define CHN 256
#define LEN 4096
#define NB_B 64            // NBR*BSZ
#define BL   65536         // BSZ*LEN
#define BN_EPS 1e-5f
#define W_EL (NBR*CHN*CHN) // 262144 elements per weight tensor
#define LT   128           // l-tile (round-7 value: the only L2-clean shape)

typedef unsigned short ushortT;
typedef unsigned short ushort4_t __attribute__((ext_vector_type(4)));
typedef unsigned short ushort8_t __attribute__((ext_vector_type(8)));
typedef short bf16x8 __attribute__((ext_vector_type(8)));
typedef float f32x4 __attribute__((ext_vector_type(4)));

__device__ __forceinline__ float bf2f(ushortT u) {
    return __uint_as_float(((unsigned)u) << 16);
}
__device__ __forceinline__ ushortT f2bf(float f) {
    unsigned b = __float_as_uint(f);
    return (ushortT)((b + 0x7FFFu + ((b >> 16) & 1u)) >> 16);
}
// order-preserving float->uint encoding (monotone); memset-0 init is below enc(-inf)
__device__ __forceinline__ unsigned encf(float f) {
    unsigned b = __float_as_uint(f);
    return (b & 0x80000000u) ? ~b : (b | 0x80000000u);
}
__device__ __forceinline__ float decf(unsigned u) {
    unsigned b = (u & 0x80000000u) ? (u ^ 0x80000000u) : ~u;
    return __uint_as_float(b);
}

// LDS swizzle for sX (byte offsets). Rows are 512B (256 c bf16). row in 0..127.
__device__ __forceinline__ int swzX(int row, int cb) {
    return row * 512 + (cb ^ ((row & 7) << 4) ^ (((row >> 3) & 3) << 7));
}

// Stage x-tile [l=128][c=256] into LDS, transposed+converted, swizzled.
// Loads are coalesced per wave-instruction (lane -> l).
__device__ __forceinline__ void stage_x_f32(const float* x, ushortT* sX, int z, int lbase, int tid)
{
    const int ls = tid & 127;
    const int gh = tid >> 7;
    const float* xp = x + (size_t)z * CHN * LEN + lbase + ls;
#pragma unroll
    for (int g = 0; g < 16; ++g) {
        int c0 = (gh * 16 + g) * 8;
        ushort8_t u;
#pragma unroll
        for (int i = 0; i < 8; ++i) u[i] = f2bf(xp[(size_t)(c0 + i) * LEN]);
        *(ushort8_t*)((char*)sX + swzX(ls, c0 * 2)) = u;
    }
}

// Fused-agg staging for ogemm: sX[l][c] = f2bf( sum_j aj[j] * v[j,b,c,l] )
// v layout [z][c][l]; reads coalesced (lane -> l), 4 slices combined in-reg.
// Numerically identical to the old agg_kernel -> restage path (same f2bf point).
__device__ __forceinline__ void stage_agg(const ushortT* v, ushortT* sX, const float aj[4],
                                          int b_, int lbase, int tid)
{
    const int ls = tid & 127;
    const int gh = tid >> 7;
    const ushortT* vp0 = v + (size_t)(0 * BSZ + b_) * CHN * LEN + lbase + ls;
    const ushortT* vp1 = v + (size_t)(1 * BSZ + b_) * CHN * LEN + lbase + ls;
    const ushortT* vp2 = v + (size_t)(2 * BSZ + b_) * CHN * LEN + lbase + ls;
    const ushortT* vp3 = v + (size_t)(3 * BSZ + b_) * CHN * LEN + lbase + ls;
#pragma unroll
    for (int g = 0; g < 16; ++g) {
        int c0 = (gh * 16 + g) * 8;
        ushort8_t u;
#pragma unroll
        for (int i = 0; i < 8; ++i) {
            size_t o = (size_t)(c0 + i) * LEN;
            float s = aj[0] * bf2f(vp0[o]) + aj[1] * bf2f(vp1[o])
                    + aj[2] * bf2f(vp2[o]) + aj[3] * bf2f(vp3[o]);
            u[i] = f2bf(s);
        }
        *(ushort8_t*)((char*)sX + swzX(ls, c0 * 2)) = u;
    }
}

// One K-chunk (64 c) of MFMA — round-7 form, NO explicit prefetch (the compiler
// schedules these loads better than any hand pipeline we tried; m141 lesson).
// W B-fragments from global in PRE-PACKED fragment order Wb2[ob][cb][lane][8]
// -> base + lane*16B = one fully-coalesced 1KB dwordx4 per wave (L2-resident).
// A = x (M=l) from LDS, B = W (N=o). acc[mf][nf] row=l col=o.
__device__ __forceinline__ void mfma_chunk_frag(const ushortT* sX, const ushortT* __restrict__ Wb2,
                                                int otile, f32x4 acc[4][4],
                                                int wr, int wc, int lane, int kb)
{
    const int am = wr * 64 + (lane & 15);
    const int kg = (lane >> 4) * 16;   // byte offset of this lane's k-group (LDS)
#pragma unroll
    for (int s = 0; s < 2; ++s) {
        const int cb = kb * 2 + s;
        bf16x8 a[4], b[4];
#pragma unroll
        for (int nf = 0; nf < 4; ++nf) {
            const int ob = otile * 8 + wc * 4 + nf;
            b[nf] = *(const bf16x8*)(Wb2 + (((size_t)ob * 8 + cb) * 64 + lane) * 8);
        }
#pragma unroll
        for (int mf = 0; mf < 4; ++mf)
            a[mf] = *(const bf16x8*)((const char*)sX + swzX(am + mf * 16, kb * 128 + s * 64 + kg));
#pragma unroll
        for (int mf = 0; mf < 4; ++mf)
#pragma unroll
            for (int nf = 0; nf < 4; ++nf)
                acc[mf][nf] = __builtin_amdgcn_mfma_f32_16x16x32_bf16(a[mf], b[nf], acc[mf][nf], 0, 0, 0);
    }
}

// ---------------------------------------------------------------------------
// QKV fused (round-7 verbatim): stage x-tile once (ONE barrier), then 6
// barrier-free GEMM-tiles with coalesced fragment-order W loads from L2.
// Wq/Wk epilogue: per-o sum & max over l -> atomics. Wv: bias + bf16 store
// to vbuf[z][c][l] (the write pattern measured at ~ideal WRITE_SIZE).
// ---------------------------------------------------------------------------
__global__ __launch_bounds__(256, 2)
void qkv_kernel(const float* __restrict__ x, const ushortT* __restrict__ Wbf,
                const float* __restrict__ bv,
                float* __restrict__ qsum, unsigned* __restrict__ qmax,
                float* __restrict__ ksum, unsigned* __restrict__ kmax,
                ushortT* __restrict__ vbuf)
{
    __shared__ ushortT sX[LT * 256];    // 64 KiB (only LDS)
    const int tid = threadIdx.x;
    const int lane = tid & 63;
    const int wv = tid >> 6;
    const int wr = wv >> 1, wc = wv & 1;
    const int lbase = blockIdx.x * LT;
    const int z = blockIdx.y;
    const int n = z >> 4;

    stage_x_f32(x, sX, z, lbase, tid);
    __syncthreads();                    // the only barrier

    const f32x4 z4 = {0.f, 0.f, 0.f, 0.f};

    for (int w = 0; w < 3; ++w) {
        const ushortT* Wb2 = Wbf + ((size_t)w * NBR + n) * CHN * CHN;
        for (int ot = 0; ot < 2; ++ot) {
            f32x4 acc[4][4];
#pragma unroll
            for (int mf = 0; mf < 4; ++mf)
#pragma unroll
                for (int nf = 0; nf < 4; ++nf) acc[mf][nf] = z4;
#pragma unroll
            for (int kb = 0; kb < 4; ++kb)
                mfma_chunk_frag(sX, Wb2, ot, acc, wr, wc, lane, kb);

            const int obase = ot * 128;
            if (w < 2) {
                float* rs = (w == 0) ? qsum : ksum;
                unsigned* rm = (w == 0) ? qmax : kmax;
#pragma unroll
                for (int nf = 0; nf < 4; ++nf) {
                    float s = 0.f, m = -3.4e38f;
#pragma unroll
                    for (int mf = 0; mf < 4; ++mf)
#pragma unroll
                        for (int r = 0; r < 4; ++r) {
                            float v = acc[mf][nf][r];
                            s += v; m = fmaxf(m, v);
                        }
                    s += __shfl_xor(s, 16); s += __shfl_xor(s, 32);
                    m = fmaxf(m, __shfl_xor(m, 16)); m = fmaxf(m, __shfl_xor(m, 32));
                    if (lane < 16) {
                        int o = obase + wc * 64 + nf * 16 + lane;
                        atomicAdd(&rs[z * CHN + o], s);
                        atomicMax(&rm[z * CHN + o], encf(m));
                    }
                }
            } else {
#pragma unroll
                for (int nf = 0; nf < 4; ++nf) {
                    int o = obase + wc * 64 + nf * 16 + (lane & 15);
                    float bvv = bv[n * CHN + o];
#pragma unroll
                    for (int mf = 0; mf < 4; ++mf) {
                        int l = lbase + wr * 64 + mf * 16 + ((lane >> 4) << 2);
                        ushort4_t u;
#pragma unroll
                        for (int r = 0; r < 4; ++r) u[r] = f2bf(acc[mf][nf][r] + bvv);
                        *(ushort4_t*)(vbuf + (size_t)(z * CHN + o) * LEN + l) = u;
                    }
                }
            }
        }
    }
}

// ---------------------------------------------------------------------------
// O GEMM with FUSED aggregation (the ONE change vs round 7): staging combines
// the 4 v-slices with attn weights in-register — the separate agg kernel and
// its 256MB intermediate round-trip are eliminated. GEMM core is round-7
// verbatim (no prefetch). 1 barrier. out_pre[z][c][l] + BN partial stats.
// ---------------------------------------------------------------------------
__global__ __launch_bounds__(256, 2)
void ogemm_kernel(const ushortT* __restrict__ v, const ushortT* __restrict__ Wbo,
                  const float* __restrict__ attn, const float* __restrict__ bo_,
                  float* __restrict__ bnsum, float* __restrict__ bnss,
                  ushortT* __restrict__ outpre)
{
    __shared__ ushortT sX[LT * 256];
    const int tid = threadIdx.x;
    const int lane = tid & 63;
    const int wv = tid >> 6;
    const int wr = wv >> 1, wc = wv & 1;
    const int lbase = blockIdx.x * LT;
    const int z = blockIdx.y;
    const int n = z >> 4;          // output branch i
    const int b_ = z & 15;
    const ushortT* Wb2 = Wbo + (size_t)n * CHN * CHN;   // per-branch slice

    float aj[4];
#pragma unroll
    for (int j = 0; j < 4; ++j) aj[j] = attn[(n * 4 + j) * BSZ + b_];

    stage_agg(v, sX, aj, b_, lbase, tid);
    __syncthreads();                    // the only barrier

    const f32x4 z4 = {0.f, 0.f, 0.f, 0.f};
    for (int ot = 0; ot < 2; ++ot) {
        f32x4 acc[4][4];
#pragma unroll
        for (int mf = 0; mf < 4; ++mf)
#pragma unroll
            for (int nf = 0; nf < 4; ++nf) acc[mf][nf] = z4;
#pragma unroll
        for (int kb = 0; kb < 4; ++kb)
            mfma_chunk_frag(sX, Wb2, ot, acc, wr, wc, lane, kb);

        const int obase = ot * 128;
#pragma unroll
        for (int nf = 0; nf < 4; ++nf) {
            int o = obase + wc * 64 + nf * 16 + (lane & 15);
            float bb = bo_[n * CHN + o];
            float s = 0.f, q2 = 0.f;
#pragma unroll
            for (int mf = 0; mf < 4; ++mf) {
                int l = lbase + wr * 64 + mf * 16 + ((lane >> 4) << 2);
                ushort4_t u;
#pragma unroll
                for (int r = 0; r < 4; ++r) {
                    float vv = acc[mf][nf][r] + bb;
                    u[r] = f2bf(vv);
                    s += vv; q2 += vv * vv;
                }
                *(ushort4_t*)(outpre + (size_t)(z * CHN + o) * LEN + l) = u;
            }
            s += __shfl_xor(s, 16); s += __shfl_xor(s, 32);
            q2 += __shfl_xor(q2, 16); q2 += __shfl_xor(q2, 32);
            if (lane < 16) {
                atomicAdd(&bnsum[n * CHN + o], s);
                atomicAdd(&bnss[n * CHN + o], q2);
            }
        }
    }
}

// convert all 4 weight tensors fp32 -> bf16 in MFMA-FRAGMENT order:
// Wbf[w][n][ob][cb][lane][8] with o = ob*16 + (lane&15), c = cb*32 + (lane>>4)*8 + j
__global__ void wcvt_kernel(const float* __restrict__ Wq, const float* __restrict__ Wk,
                            const float* __restrict__ Wv, const float* __restrict__ Wo,
                            ushortT* __restrict__ Wbf)
{
    int t = blockIdx.x * 256 + threadIdx.x;    // one thread per 8-elem fragment slice
    if (t < 4 * (W_EL / 8)) {
        const float* srcs[4] = {Wq, Wk, Wv, Wo};
        int w    = t >> 15;          // W_EL/8 = 32768 per tensor
        int r    = t & 32767;
        int lane = r & 63;
        int cb   = (r >> 6) & 7;
        int ob   = (r >> 9) & 15;
        int n    = r >> 13;
        const float* src = srcs[w] + (size_t)n * CHN * CHN;
        int o = ob * 16 + (lane & 15);
        int c = cb * 32 + (lane >> 4) * 8;
        float4 f0 = *(const float4*)(src + (size_t)o * CHN + c);
        float4 f1 = *(const float4*)(src + (size_t)o * CHN + c + 4);
        ushort8_t u = {f2bf(f0.x), f2bf(f0.y), f2bf(f0.z), f2bf(f0.w),
                       f2bf(f1.x), f2bf(f1.y), f2bf(f1.z), f2bf(f1.w)};
        *(ushort8_t*)(Wbf + ((size_t)w * NBR + n) * CHN * CHN
                          + (((size_t)ob * 8 + cb) * 64 + lane) * 8) = u;
    }
}

// ---------------------------------------------------------------------------
// attention coefficients: scores[i,j,b] = (sum_c sq*sk) * edge_w[i,j] / 64
// attn[i,j,b] = softmax_j(scores) * softmax(branch_imp)[j]
// sq = qsum/L + dec(qmax) + 2*bq  (mean+max, bias shifts both by bq)
// ---------------------------------------------------------------------------
__global__ void attn_kernel(const float* __restrict__ qsum, const unsigned* __restrict__ qmax,
                            const float* __restrict__ ksum, const unsigned* __restrict__ kmax,
                            const float* __restrict__ bq, const float* __restrict__ bk,
                            const float* __restrict__ edge, const float* __restrict__ bimp,
                            float* __restrict__ attn)
{
    __shared__ float sc[NBR][NBR][BSZ];
    int tid = threadIdx.x;           // 256 threads == 4*4*16
    int i = tid >> 6, j = (tid >> 4) & 3, b = tid & 15;
    float s = 0.f;
    const float invL = 1.0f / (float)LEN;
    for (int c = 0; c < CHN; ++c) {
        int qi = (i * BSZ + b) * CHN + c;
        int ki = (j * BSZ + b) * CHN + c;
        float sq = qsum[qi] * invL + decf(qmax[qi]) + 2.f * bq[i * CHN + c];
        float sk = ksum[ki] * invL + decf(kmax[ki]) + 2.f * bk[j * CHN + c];
        s += sq * sk;
    }
    sc[i][j][b] = s * edge[i * 4 + j] * (1.0f / 64.0f);
    __syncthreads();
    if (tid < 64) {
        int ii = tid >> 4, bb = tid & 15;
        float m = -3.4e38f;
        for (int jj = 0; jj < 4; ++jj) m = fmaxf(m, sc[ii][jj][bb]);
        float e[4]; float sum = 0.f;
        for (int jj = 0; jj < 4; ++jj) { e[jj] = __expf(sc[ii][jj][bb] - m); sum += e[jj]; }
        float bm = fmaxf(fmaxf(bimp[0], bimp[1]), fmaxf(bimp[2], bimp[3]));
        float be[4]; float bs = 0.f;
        for (int jj = 0; jj < 4; ++jj) { be[jj] = __expf(bimp[jj] - bm); bs += be[jj]; }
        for (int jj = 0; jj < 4; ++jj)
            attn[(ii * 4 + jj) * BSZ + bb] = (e[jj] / sum) * (be[jj] / bs);
    }
}

// finalize BN affine: scale = gamma*rsqrt(var+eps), shift = beta - mean*scale
__global__ void bnfin_kernel(const float* __restrict__ bnsum, const float* __restrict__ bnss,
                             const float* __restrict__ gamma, const float* __restrict__ beta,
                             float* __restrict__ scl, float* __restrict__ shf)
{
    int t = blockIdx.x * blockDim.x + threadIdx.x;   // 0..1023 = n*256+c
    if (t < NBR * CHN) {
        const float inv = 1.0f / (float)BL;
        float mean = bnsum[t] * inv;
        float var = bnss[t] * inv - mean * mean;
        float rs = rsqrtf(var + BN_EPS);
        float s = gamma[t] * rs;
        scl[t] = s;
        shf[t] = beta[t] - mean * s;
    }
}

// out = relu(out_pre*scale + shift) + x
__global__ __launch_bounds__(256)
void final_kernel(const ushortT* __restrict__ outpre, const float* __restrict__ x,
                  const float* __restrict__ scl, const float* __restrict__ shf,
                  float* __restrict__ out)
{
    const long long U = (long long)NB_B * CHN * (LEN / 8);   // 8,388,608 units of 8
    for (long long u = (long long)blockIdx.x * blockDim.x + threadIdx.x; u < U;
         u += (long long)gridDim.x * blockDim.x) {
        int l0 = (int)(u & 511) * 8;
        int c  = (int)(u >> 9) & 255;
        int zz = (int)(u >> 17);          // n*16+b
        int n  = zz >> 4;
        size_t base = ((size_t)zz * CHN + c) * LEN + l0;
        ushort8_t op = *(const ushort8_t*)(outpre + base);
        float4 x0 = *(const float4*)(x + base);
        float4 x1 = *(const float4*)(x + base + 4);
        float sc = scl[n * CHN + c];
        float sh = shf[n * CHN + c];
        float xr[8] = {x0.x, x0.y, x0.z, x0.w, x1.x, x1.y, x1.z, x1.w};
        float res[8];
#pragma unroll
        for (int e = 0; e < 8; ++e) {
            float bn = bf2f(op[e]) * sc + sh;
            res[e] = fmaxf(bn, 0.f) + xr[e];
        }
        float4 o0 = {res[0], res[1], res[2], res[3]};
        float4 o1 = {res[4], res[5], res[6], res[7]};
        *(float4*)(out + base) = o0;
        *(float4*)(out + base + 4) = o1;
    }
}

extern "C" void kernel_launch(void* const* d_in, const int* in_sizes, int n_in,
                              void* d_out, int out_size, void* d_ws, size_t ws_size,
                              hipStream_t stream)
{
    const float* x     = (const float*)d_in[0];
    const float* Wq    = (const float*)d_in[1];
    const float* bq    = (const float*)d_in[2];
    const float* Wk    = (const float*)d_in[3];
    const float* bk    = (const float*)d_in[4];
    const float* Wv    = (const float*)d_in[5];
    const float* bv    = (const float*)d_in[6];
    const float* Wo    = (const float*)d_in[7];
    const float* bo    = (const float*)d_in[8];
    const float* gamma = (const float*)d_in[9];
    const float* beta  = (const float*)d_in[10];
    const float* edge  = (const float*)d_in[11];
    const float* bimp  = (const float*)d_in[12];

    char* ws = (char*)d_ws;
    const size_t P_BYTES = (size_t)NBR * BSZ * CHN * LEN * 2;   // 128 MiB (bf16)
    ushortT* outpre = (ushortT*)ws;          // out_pre staging (ws[0:128Mi])
    size_t off = P_BYTES;
    float*    qsum = (float*)(ws + off);    off += 65536;
    unsigned* qmax = (unsigned*)(ws + off); off += 65536;
    float*    ksum = (float*)(ws + off);    off += 65536;
    unsigned* kmax = (unsigned*)(ws + off); off += 65536;
    float*    attn = (float*)(ws + off);    off += 1024;
    float*    bnsum= (float*)(ws + off);    off += 4096;
    float*    bnss = (float*)(ws + off);    off += 4096;
    float*    scl  = (float*)(ws + off);    off += 4096;
    float*    shf  = (float*)(ws + off);    off += 4096;

    // zero the small accumulators (sum=0; max uses encoding where 0 < enc(-inf))
    hipMemsetAsync(ws + P_BYTES, 0, off - P_BYTES, stream);

    // d_out scratch (all dead before final_kernel rewrites d_out):
    //   [0, 128Mi):    v (bf16, [z][c][l]) written by qkv, read by ogemm
    //   [128Mi, +2Mi): Wbf (bf16 weights, fragment order) written by wcvt
    ushortT* vbuf = (ushortT*)d_out;
    ushortT* Wbf  = (ushortT*)((char*)d_out + ((size_t)134217728));
    float*   outf = (float*)d_out;

    wcvt_kernel<<<(4 * (W_EL / 8) + 255) / 256, 256, 0, stream>>>(Wq, Wk, Wv, Wo, Wbf);

    dim3 gq(LEN / LT, NB_B);   // (32, 64)
    qkv_kernel<<<gq, 256, 0, stream>>>(x, Wbf, bv, qsum, qmax, ksum, kmax, vbuf);
    attn_kernel<<<1, 256, 0, stream>>>(qsum, qmax, ksum, kmax, bq, bk, edge, bimp, attn);
    ogemm_kernel<<<gq, 256, 0, stream>>>(vbuf, Wbf + (size_t)3 * W_EL, attn, bo, bnsum, bnss, outpre);
    bnfin_kernel<<<4, 256, 0, stream>>>(bnsum, bnss, gamma, beta, scl, shf);
    final_kernel<<<8192, 256, 0, stream>>>(outpre, x, scl, shf, outf);
}

// Round 14
// 496.876 us; speedup vs baseline: 1.8058x; 1.0396x over previous
//
#include <hip/hip_runtime.h>
#include <stdint.h>
#include <stddef.h>

// Problem constants (reference: NB=4, B=16, C=256, L=4096)
#define NBR 4
#define BSZ 16
#define CHN 256
#define LEN 4096
#define NB_B 64            // NBR*BSZ
#define BL   65536         // BSZ*LEN
#define BN_EPS 1e-5f
#define W_EL (NBR*CHN*CHN) // 262144 elements per weight tensor
#define LT   128           // l-tile (round-7 value: the only L2-clean shape)

typedef unsigned short ushortT;
typedef unsigned short ushort4_t __attribute__((ext_vector_type(4)));
typedef unsigned short ushort8_t __attribute__((ext_vector_type(8)));
typedef short bf16x8 __attribute__((ext_vector_type(8)));
typedef float f32x4 __attribute__((ext_vector_type(4)));

__device__ __forceinline__ float bf2f(ushortT u) {
    return __uint_as_float(((unsigned)u) << 16);
}
__device__ __forceinline__ ushortT f2bf(float f) {
    unsigned b = __float_as_uint(f);
    return (ushortT)((b + 0x7FFFu + ((b >> 16) & 1u)) >> 16);
}
// order-preserving float->uint encoding (monotone); memset-0 init is below enc(-inf)
__device__ __forceinline__ unsigned encf(float f) {
    unsigned b = __float_as_uint(f);
    return (b & 0x80000000u) ? ~b : (b | 0x80000000u);
}
__device__ __forceinline__ float decf(unsigned u) {
    unsigned b = (u & 0x80000000u) ? (u ^ 0x80000000u) : ~u;
    return __uint_as_float(b);
}

// LDS swizzle for sX (byte offsets). Rows are 512B (256 c bf16). row in 0..127.
// All XOR terms are >=16, so any 2B element at even offset maps consistently
// with the 16B-aligned fragment reads.
__device__ __forceinline__ int swzX(int row, int cb) {
    return row * 512 + (cb ^ ((row & 7) << 4) ^ (((row >> 3) & 3) << 7));
}

// Stage x-tile [l=128][c=256] into LDS, transposed+converted, swizzled.
// Loads are coalesced per wave-instruction (lane -> l).
__device__ __forceinline__ void stage_x_f32(const float* x, ushortT* sX, int z, int lbase, int tid)
{
    const int ls = tid & 127;
    const int gh = tid >> 7;
    const float* xp = x + (size_t)z * CHN * LEN + lbase + ls;
#pragma unroll
    for (int g = 0; g < 16; ++g) {
        int c0 = (gh * 16 + g) * 8;
        ushort8_t u;
#pragma unroll
        for (int i = 0; i < 8; ++i) u[i] = f2bf(xp[(size_t)(c0 + i) * LEN]);
        *(ushort8_t*)((char*)sX + swzX(ls, c0 * 2)) = u;
    }
}

// Fused-agg staging for ogemm, VECTORIZED (round-14 change):
// thread -> (c, l-group of 8). Each pass: 4x ushort8 (16B) reads along l
// (v layout [z][c][l] is l-contiguous -> coalesced), in-reg combine with attn
// weights, 8 scalar bf16 LDS writes (stride-8 rows spread by the (row>>3)
// XOR term -> ~4-way conflict, negligible). 64 vector loads/thread replaces
// round-13's 512 scalar loads/thread. Numerics identical (same f2bf point).
__device__ __forceinline__ void stage_agg(const ushortT* v, ushortT* sX, const float aj[4],
                                          int b_, int lbase, int tid)
{
    const ushortT* vb0 = v + (size_t)(0 * BSZ + b_) * CHN * LEN;
    const ushortT* vb1 = v + (size_t)(1 * BSZ + b_) * CHN * LEN;
    const ushortT* vb2 = v + (size_t)(2 * BSZ + b_) * CHN * LEN;
    const ushortT* vb3 = v + (size_t)(3 * BSZ + b_) * CHN * LEN;
#pragma unroll 4
    for (int pass = 0; pass < 16; ++pass) {
        int idx = pass * 256 + tid;        // 0..4095
        int c   = idx >> 4;                // 0..255
        int lg  = idx & 15;                // l-group: l0 = lg*8
        size_t base = (size_t)c * LEN + lbase + lg * 8;
        ushort8_t r0 = *(const ushort8_t*)(vb0 + base);
        ushort8_t r1 = *(const ushort8_t*)(vb1 + base);
        ushort8_t r2 = *(const ushort8_t*)(vb2 + base);
        ushort8_t r3 = *(const ushort8_t*)(vb3 + base);
#pragma unroll
        for (int e = 0; e < 8; ++e) {
            float s = aj[0] * bf2f(r0[e]) + aj[1] * bf2f(r1[e])
                    + aj[2] * bf2f(r2[e]) + aj[3] * bf2f(r3[e]);
            int row = lg * 8 + e;
            *(ushortT*)((char*)sX + swzX(row, c * 2)) = f2bf(s);
        }
    }
}

// One K-chunk (64 c) of MFMA — round-7 form, NO explicit prefetch (the compiler
// schedules these loads better than any hand pipeline we tried; m141 lesson).
// W B-fragments from global in PRE-PACKED fragment order Wb2[ob][cb][lane][8]
// -> base + lane*16B = one fully-coalesced 1KB dwordx4 per wave (L2-resident).
// A = x (M=l) from LDS, B = W (N=o). acc[mf][nf] row=l col=o.
__device__ __forceinline__ void mfma_chunk_frag(const ushortT* sX, const ushortT* __restrict__ Wb2,
                                                int otile, f32x4 acc[4][4],
                                                int wr, int wc, int lane, int kb)
{
    const int am = wr * 64 + (lane & 15);
    const int kg = (lane >> 4) * 16;   // byte offset of this lane's k-group (LDS)
#pragma unroll
    for (int s = 0; s < 2; ++s) {
        const int cb = kb * 2 + s;
        bf16x8 a[4], b[4];
#pragma unroll
        for (int nf = 0; nf < 4; ++nf) {
            const int ob = otile * 8 + wc * 4 + nf;
            b[nf] = *(const bf16x8*)(Wb2 + (((size_t)ob * 8 + cb) * 64 + lane) * 8);
        }
#pragma unroll
        for (int mf = 0; mf < 4; ++mf)
            a[mf] = *(const bf16x8*)((const char*)sX + swzX(am + mf * 16, kb * 128 + s * 64 + kg));
#pragma unroll
        for (int mf = 0; mf < 4; ++mf)
#pragma unroll
            for (int nf = 0; nf < 4; ++nf)
                acc[mf][nf] = __builtin_amdgcn_mfma_f32_16x16x32_bf16(a[mf], b[nf], acc[mf][nf], 0, 0, 0);
    }
}

// ---------------------------------------------------------------------------
// QKV fused (round-7 verbatim, UNTOUCHED): stage x-tile once (ONE barrier),
// then 6 barrier-free GEMM-tiles with coalesced fragment-order W loads.
// Wq/Wk epilogue: per-o sum & max over l -> atomics. Wv: bias + bf16 store
// to vbuf[z][c][l] (the write pattern measured at ~ideal WRITE_SIZE).
// ---------------------------------------------------------------------------
__global__ __launch_bounds__(256, 2)
void qkv_kernel(const float* __restrict__ x, const ushortT* __restrict__ Wbf,
                const float* __restrict__ bv,
                float* __restrict__ qsum, unsigned* __restrict__ qmax,
                float* __restrict__ ksum, unsigned* __restrict__ kmax,
                ushortT* __restrict__ vbuf)
{
    __shared__ ushortT sX[LT * 256];    // 64 KiB (only LDS)
    const int tid = threadIdx.x;
    const int lane = tid & 63;
    const int wv = tid >> 6;
    const int wr = wv >> 1, wc = wv & 1;
    const int lbase = blockIdx.x * LT;
    const int z = blockIdx.y;
    const int n = z >> 4;

    stage_x_f32(x, sX, z, lbase, tid);
    __syncthreads();                    // the only barrier

    const f32x4 z4 = {0.f, 0.f, 0.f, 0.f};

    for (int w = 0; w < 3; ++w) {
        const ushortT* Wb2 = Wbf + ((size_t)w * NBR + n) * CHN * CHN;
        for (int ot = 0; ot < 2; ++ot) {
            f32x4 acc[4][4];
#pragma unroll
            for (int mf = 0; mf < 4; ++mf)
#pragma unroll
                for (int nf = 0; nf < 4; ++nf) acc[mf][nf] = z4;
#pragma unroll
            for (int kb = 0; kb < 4; ++kb)
                mfma_chunk_frag(sX, Wb2, ot, acc, wr, wc, lane, kb);

            const int obase = ot * 128;
            if (w < 2) {
                float* rs = (w == 0) ? qsum : ksum;
                unsigned* rm = (w == 0) ? qmax : kmax;
#pragma unroll
                for (int nf = 0; nf < 4; ++nf) {
                    float s = 0.f, m = -3.4e38f;
#pragma unroll
                    for (int mf = 0; mf < 4; ++mf)
#pragma unroll
                        for (int r = 0; r < 4; ++r) {
                            float v = acc[mf][nf][r];
                            s += v; m = fmaxf(m, v);
                        }
                    s += __shfl_xor(s, 16); s += __shfl_xor(s, 32);
                    m = fmaxf(m, __shfl_xor(m, 16)); m = fmaxf(m, __shfl_xor(m, 32));
                    if (lane < 16) {
                        int o = obase + wc * 64 + nf * 16 + lane;
                        atomicAdd(&rs[z * CHN + o], s);
                        atomicMax(&rm[z * CHN + o], encf(m));
                    }
                }
            } else {
#pragma unroll
                for (int nf = 0; nf < 4; ++nf) {
                    int o = obase + wc * 64 + nf * 16 + (lane & 15);
                    float bvv = bv[n * CHN + o];
#pragma unroll
                    for (int mf = 0; mf < 4; ++mf) {
                        int l = lbase + wr * 64 + mf * 16 + ((lane >> 4) << 2);
                        ushort4_t u;
#pragma unroll
                        for (int r = 0; r < 4; ++r) u[r] = f2bf(acc[mf][nf][r] + bvv);
                        *(ushort4_t*)(vbuf + (size_t)(z * CHN + o) * LEN + l) = u;
                    }
                }
            }
        }
    }
}

// ---------------------------------------------------------------------------
// O GEMM with FUSED aggregation: staging combines the 4 v-slices with attn
// weights in-register, now with vectorized 16B v reads (round-14 change).
// GEMM core is round-7 verbatim. 1 barrier. out_pre[z][c][l] + BN stats.
// ---------------------------------------------------------------------------
__global__ __launch_bounds__(256, 2)
void ogemm_kernel(const ushortT* __restrict__ v, const ushortT* __restrict__ Wbo,
                  const float* __restrict__ attn, const float* __restrict__ bo_,
                  float* __restrict__ bnsum, float* __restrict__ bnss,
                  ushortT* __restrict__ outpre)
{
    __shared__ ushortT sX[LT * 256];
    const int tid = threadIdx.x;
    const int lane = tid & 63;
    const int wv = tid >> 6;
    const int wr = wv >> 1, wc = wv & 1;
    const int lbase = blockIdx.x * LT;
    const int z = blockIdx.y;
    const int n = z >> 4;          // output branch i
    const int b_ = z & 15;
    const ushortT* Wb2 = Wbo + (size_t)n * CHN * CHN;   // per-branch slice

    float aj[4];
#pragma unroll
    for (int j = 0; j < 4; ++j) aj[j] = attn[(n * 4 + j) * BSZ + b_];

    stage_agg(v, sX, aj, b_, lbase, tid);
    __syncthreads();                    // the only barrier

    const f32x4 z4 = {0.f, 0.f, 0.f, 0.f};
    for (int ot = 0; ot < 2; ++ot) {
        f32x4 acc[4][4];
#pragma unroll
        for (int mf = 0; mf < 4; ++mf)
#pragma unroll
            for (int nf = 0; nf < 4; ++nf) acc[mf][nf] = z4;
#pragma unroll
        for (int kb = 0; kb < 4; ++kb)
            mfma_chunk_frag(sX, Wb2, ot, acc, wr, wc, lane, kb);

        const int obase = ot * 128;
#pragma unroll
        for (int nf = 0; nf < 4; ++nf) {
            int o = obase + wc * 64 + nf * 16 + (lane & 15);
            float bb = bo_[n * CHN + o];
            float s = 0.f, q2 = 0.f;
#pragma unroll
            for (int mf = 0; mf < 4; ++mf) {
                int l = lbase + wr * 64 + mf * 16 + ((lane >> 4) << 2);
                ushort4_t u;
#pragma unroll
                for (int r = 0; r < 4; ++r) {
                    float vv = acc[mf][nf][r] + bb;
                    u[r] = f2bf(vv);
                    s += vv; q2 += vv * vv;
                }
                *(ushort4_t*)(outpre + (size_t)(z * CHN + o) * LEN + l) = u;
            }
            s += __shfl_xor(s, 16); s += __shfl_xor(s, 32);
            q2 += __shfl_xor(q2, 16); q2 += __shfl_xor(q2, 32);
            if (lane < 16) {
                atomicAdd(&bnsum[n * CHN + o], s);
                atomicAdd(&bnss[n * CHN + o], q2);
            }
        }
    }
}

// convert all 4 weight tensors fp32 -> bf16 in MFMA-FRAGMENT order:
// Wbf[w][n][ob][cb][lane][8] with o = ob*16 + (lane&15), c = cb*32 + (lane>>4)*8 + j
__global__ void wcvt_kernel(const float* __restrict__ Wq, const float* __restrict__ Wk,
                            const float* __restrict__ Wv, const float* __restrict__ Wo,
                            ushortT* __restrict__ Wbf)
{
    int t = blockIdx.x * 256 + threadIdx.x;    // one thread per 8-elem fragment slice
    if (t < 4 * (W_EL / 8)) {
        const float* srcs[4] = {Wq, Wk, Wv, Wo};
        int w    = t >> 15;          // W_EL/8 = 32768 per tensor
        int r    = t & 32767;
        int lane = r & 63;
        int cb   = (r >> 6) & 7;
        int ob   = (r >> 9) & 15;
        int n    = r >> 13;
        const float* src = srcs[w] + (size_t)n * CHN * CHN;
        int o = ob * 16 + (lane & 15);
        int c = cb * 32 + (lane >> 4) * 8;
        float4 f0 = *(const float4*)(src + (size_t)o * CHN + c);
        float4 f1 = *(const float4*)(src + (size_t)o * CHN + c + 4);
        ushort8_t u = {f2bf(f0.x), f2bf(f0.y), f2bf(f0.z), f2bf(f0.w),
                       f2bf(f1.x), f2bf(f1.y), f2bf(f1.z), f2bf(f1.w)};
        *(ushort8_t*)(Wbf + ((size_t)w * NBR + n) * CHN * CHN
                          + (((size_t)ob * 8 + cb) * 64 + lane) * 8) = u;
    }
}

// ---------------------------------------------------------------------------
// attention coefficients: scores[i,j,b] = (sum_c sq*sk) * edge_w[i,j] / 64
// attn[i,j,b] = softmax_j(scores) * softmax(branch_imp)[j]
// sq = qsum/L + dec(qmax) + 2*bq  (mean+max, bias shifts both by bq)
// ---------------------------------------------------------------------------
__global__ void attn_kernel(const float* __restrict__ qsum, const unsigned* __restrict__ qmax,
                            const float* __restrict__ ksum, const unsigned* __restrict__ kmax,
                            const float* __restrict__ bq, const float* __restrict__ bk,
                            const float* __restrict__ edge, const float* __restrict__ bimp,
                            float* __restrict__ attn)
{
    __shared__ float sc[NBR][NBR][BSZ];
    int tid = threadIdx.x;           // 256 threads == 4*4*16
    int i = tid >> 6, j = (tid >> 4) & 3, b = tid & 15;
    float s = 0.f;
    const float invL = 1.0f / (float)LEN;
    for (int c = 0; c < CHN; ++c) {
        int qi = (i * BSZ + b) * CHN + c;
        int ki = (j * BSZ + b) * CHN + c;
        float sq = qsum[qi] * invL + decf(qmax[qi]) + 2.f * bq[i * CHN + c];
        float sk = ksum[ki] * invL + decf(kmax[ki]) + 2.f * bk[j * CHN + c];
        s += sq * sk;
    }
    sc[i][j][b] = s * edge[i * 4 + j] * (1.0f / 64.0f);
    __syncthreads();
    if (tid < 64) {
        int ii = tid >> 4, bb = tid & 15;
        float m = -3.4e38f;
        for (int jj = 0; jj < 4; ++jj) m = fmaxf(m, sc[ii][jj][bb]);
        float e[4]; float sum = 0.f;
        for (int jj = 0; jj < 4; ++jj) { e[jj] = __expf(sc[ii][jj][bb] - m); sum += e[jj]; }
        float bm = fmaxf(fmaxf(bimp[0], bimp[1]), fmaxf(bimp[2], bimp[3]));
        float be[4]; float bs = 0.f;
        for (int jj = 0; jj < 4; ++jj) { be[jj] = __expf(bimp[jj] - bm); bs += be[jj]; }
        for (int jj = 0; jj < 4; ++jj)
            attn[(ii * 4 + jj) * BSZ + bb] = (e[jj] / sum) * (be[jj] / bs);
    }
}

// finalize BN affine: scale = gamma*rsqrt(var+eps), shift = beta - mean*scale
__global__ void bnfin_kernel(const float* __restrict__ bnsum, const float* __restrict__ bnss,
                             const float* __restrict__ gamma, const float* __restrict__ beta,
                             float* __restrict__ scl, float* __restrict__ shf)
{
    int t = blockIdx.x * blockDim.x + threadIdx.x;   // 0..1023 = n*256+c
    if (t < NBR * CHN) {
        const float inv = 1.0f / (float)BL;
        float mean = bnsum[t] * inv;
        float var = bnss[t] * inv - mean * mean;
        float rs = rsqrtf(var + BN_EPS);
        float s = gamma[t] * rs;
        scl[t] = s;
        shf[t] = beta[t] - mean * s;
    }
}

// out = relu(out_pre*scale + shift) + x
__global__ __launch_bounds__(256)
void final_kernel(const ushortT* __restrict__ outpre, const float* __restrict__ x,
                  const float* __restrict__ scl, const float* __restrict__ shf,
                  float* __restrict__ out)
{
    const long long U = (long long)NB_B * CHN * (LEN / 8);   // 8,388,608 units of 8
    for (long long u = (long long)blockIdx.x * blockDim.x + threadIdx.x; u < U;
         u += (long long)gridDim.x * blockDim.x) {
        int l0 = (int)(u & 511) * 8;
        int c  = (int)(u >> 9) & 255;
        int zz = (int)(u >> 17);          // n*16+b
        int n  = zz >> 4;
        size_t base = ((size_t)zz * CHN + c) * LEN + l0;
        ushort8_t op = *(const ushort8_t*)(outpre + base);
        float4 x0 = *(const float4*)(x + base);
        float4 x1 = *(const float4*)(x + base + 4);
        float sc = scl[n * CHN + c];
        float sh = shf[n * CHN + c];
        float xr[8] = {x0.x, x0.y, x0.z, x0.w, x1.x, x1.y, x1.z, x1.w};
        float res[8];
#pragma unroll
        for (int e = 0; e < 8; ++e) {
            float bn = bf2f(op[e]) * sc + sh;
            res[e] = fmaxf(bn, 0.f) + xr[e];
        }
        float4 o0 = {res[0], res[1], res[2], res[3]};
        float4 o1 = {res[4], res[5], res[6], res[7]};
        *(float4*)(out + base) = o0;
        *(float4*)(out + base + 4) = o1;
    }
}

extern "C" void kernel_launch(void* const* d_in, const int* in_sizes, int n_in,
                              void* d_out, int out_size, void* d_ws, size_t ws_size,
                              hipStream_t stream)
{
    const float* x     = (const float*)d_in[0];
    const float* Wq    = (const float*)d_in[1];
    const float* bq    = (const float*)d_in[2];
    const float* Wk    = (const float*)d_in[3];
    const float* bk    = (const float*)d_in[4];
    const float* Wv    = (const float*)d_in[5];
    const float* bv    = (const float*)d_in[6];
    const float* Wo    = (const float*)d_in[7];
    const float* bo    = (const float*)d_in[8];
    const float* gamma = (const float*)d_in[9];
    const float* beta  = (const float*)d_in[10];
    const float* edge  = (const float*)d_in[11];
    const float* bimp  = (const float*)d_in[12];

    char* ws = (char*)d_ws;
    const size_t P_BYTES = (size_t)NBR * BSZ * CHN * LEN * 2;   // 128 MiB (bf16)
    ushortT* outpre = (ushortT*)ws;          // out_pre staging (ws[0:128Mi])
    size_t off = P_BYTES;
    float*    qsum = (float*)(ws + off);    off += 65536;
    unsigned* qmax = (unsigned*)(ws + off); off += 65536;
    float*    ksum = (float*)(ws + off);    off += 65536;
    unsigned* kmax = (unsigned*)(ws + off); off += 65536;
    float*    attn = (float*)(ws + off);    off += 1024;
    float*    bnsum= (float*)(ws + off);    off += 4096;
    float*    bnss = (float*)(ws + off);    off += 4096;
    float*    scl  = (float*)(ws + off);    off += 4096;
    float*    shf  = (float*)(ws + off);    off += 4096;

    // zero the small accumulators (sum=0; max uses encoding where 0 < enc(-inf))
    hipMemsetAsync(ws + P_BYTES, 0, off - P_BYTES, stream);

    // d_out scratch (all dead before final_kernel rewrites d_out):
    //   [0, 128Mi):    v (bf16, [z][c][l]) written by qkv, read by ogemm
    //   [128Mi, +2Mi): Wbf (bf16 weights, fragment order) written by wcvt
    ushortT* vbuf = (ushortT*)d_out;
    ushortT* Wbf  = (ushortT*)((char*)d_out + ((size_t)134217728));
    float*   outf = (float*)d_out;

    wcvt_kernel<<<(4 * (W_EL / 8) + 255) / 256, 256, 0, stream>>>(Wq, Wk, Wv, Wo, Wbf);

    dim3 gq(LEN / LT, NB_B);   // (32, 64)
    qkv_kernel<<<gq, 256, 0, stream>>>(x, Wbf, bv, qsum, qmax, ksum, kmax, vbuf);
    attn_kernel<<<1, 256, 0, stream>>>(qsum, qmax, ksum, kmax, bq, bk, edge, bimp, attn);
    ogemm_kernel<<<gq, 256, 0, stream>>>(vbuf, Wbf + (size_t)3 * W_EL, attn, bo, bnsum, bnss, outpre);
    bnfin_kernel<<<4, 256, 0, stream>>>(bnsum, bnss, gamma, beta, scl, shf);
    final_kernel<<<8192, 256, 0, stream>>>(outpre, x, scl, shf, outf);
}

// Round 15
// 492.730 us; speedup vs baseline: 1.8210x; 1.0084x over previous
//
#include <hip/hip_runtime.h>
#include <stdint.h>
#include <stddef.h>

// Problem constants (reference: NB=4, B=16, C=256, L=4096)
#define NBR 4
#define BSZ 16
#define CHN 256
#define LEN 4096
#define NB_B 64            // NBR*BSZ
#define BL   65536         // BSZ*LEN
#define BN_EPS 1e-5f
#define W_EL (NBR*CHN*CHN) // 262144 elements per weight tensor
#define LT   128           // l-tile (round-7 value: the only L2-clean shape)

typedef unsigned short ushortT;
typedef unsigned short ushort4_t __attribute__((ext_vector_type(4)));
typedef unsigned short ushort8_t __attribute__((ext_vector_type(8)));
typedef short bf16x8 __attribute__((ext_vector_type(8)));
typedef float f32x4 __attribute__((ext_vector_type(4)));

__device__ __forceinline__ float bf2f(ushortT u) {
    return __uint_as_float(((unsigned)u) << 16);
}
__device__ __forceinline__ ushortT f2bf(float f) {
    unsigned b = __float_as_uint(f);
    return (ushortT)((b + 0x7FFFu + ((b >> 16) & 1u)) >> 16);
}
// order-preserving float->uint encoding (monotone); memset-0 init is below enc(-inf)
__device__ __forceinline__ unsigned encf(float f) {
    unsigned b = __float_as_uint(f);
    return (b & 0x80000000u) ? ~b : (b | 0x80000000u);
}
__device__ __forceinline__ float decf(unsigned u) {
    unsigned b = (u & 0x80000000u) ? (u ^ 0x80000000u) : ~u;
    return __uint_as_float(b);
}

// LDS swizzle for sX (byte offsets). Rows are 512B (256 c bf16). row in 0..127.
// XOR terms are 16B/128B-aligned, so 8B-aligned sub-writes stay consistent
// with the 16B-aligned fragment reads.
__device__ __forceinline__ int swzX(int row, int cb) {
    return row * 512 + (cb ^ ((row & 7) << 4) ^ (((row >> 3) & 3) << 7));
}

// Stage x-tile [l=128][c=256] into LDS, transposed+converted, swizzled.
// Loads are coalesced per wave-instruction (lane -> l).
__device__ __forceinline__ void stage_x_f32(const float* x, ushortT* sX, int z, int lbase, int tid)
{
    const int ls = tid & 127;
    const int gh = tid >> 7;
    const float* xp = x + (size_t)z * CHN * LEN + lbase + ls;
#pragma unroll
    for (int g = 0; g < 16; ++g) {
        int c0 = (gh * 16 + g) * 8;
        ushort8_t u;
#pragma unroll
        for (int i = 0; i < 8; ++i) u[i] = f2bf(xp[(size_t)(c0 + i) * LEN]);
        *(ushort8_t*)((char*)sX + swzX(ls, c0 * 2)) = u;
    }
}

// Fused-agg staging, round-15: vector global reads (16B along l, coalesced)
// PLUS conflict-free LDS writes via a per-wave scratch transpose.
//   pass: wave covers 4 c x 128 l.
//   (1) 4x ushort8 v reads, in-reg combine with attn weights -> ushort8
//   (2) write l-contiguous to wave-private padded scratch (264B rows, ~2-way)
//   (3) re-read transposed (lanes contiguous in l -> conflict-free) and write
//       ushort4 (4 contiguous c) to swizzled sX (banks spread by (row&7)<<4
//       XOR -> ~4-way, free-ish).
// Same-wave LDS dependences only -> no barriers; compiler inserts lgkmcnt.
// Round-14's 2B scatter-writes hit row*512 bank alignment -> ~32-way conflict;
// this replaces them. Numerics identical (same f2bf points).
__device__ __forceinline__ void stage_agg(const ushortT* v, ushortT* sX, ushortT* sT,
                                          const float aj[4], int b_, int lbase, int tid)
{
    const int lane = tid & 63;
    const int wave = tid >> 6;
    const int c4   = lane >> 4;        // 0..3: c within the wave's 4-c group
    const int lg   = lane & 15;        // l-octet
    ushortT* tw = sT + wave * 528;     // 1056B per wave, rows padded to 264B
    const ushortT* vb0 = v + (size_t)(0 * BSZ + b_) * CHN * LEN;
    const ushortT* vb1 = v + (size_t)(1 * BSZ + b_) * CHN * LEN;
    const ushortT* vb2 = v + (size_t)(2 * BSZ + b_) * CHN * LEN;
    const ushortT* vb3 = v + (size_t)(3 * BSZ + b_) * CHN * LEN;
#pragma unroll 2
    for (int pass = 0; pass < 16; ++pass) {
        const int c = pass * 16 + wave * 4 + c4;
        const size_t base = (size_t)c * LEN + lbase + lg * 8;
        ushort8_t r0 = *(const ushort8_t*)(vb0 + base);
        ushort8_t r1 = *(const ushort8_t*)(vb1 + base);
        ushort8_t r2 = *(const ushort8_t*)(vb2 + base);
        ushort8_t r3 = *(const ushort8_t*)(vb3 + base);
        ushort8_t u;
#pragma unroll
        for (int e = 0; e < 8; ++e) {
            float s = aj[0] * bf2f(r0[e]) + aj[1] * bf2f(r1[e])
                    + aj[2] * bf2f(r2[e]) + aj[3] * bf2f(r3[e]);
            u[e] = f2bf(s);
        }
        *(ushort8_t*)(tw + c4 * 132 + lg * 8) = u;      // l-contiguous scratch write

        const int cb = pass * 32 + wave * 8;             // byte offset of 4-c group
#pragma unroll
        for (int sub = 0; sub < 2; ++sub) {
            const int row = sub * 64 + lane;             // 0..127
            ushort4_t t;
#pragma unroll
            for (int cc = 0; cc < 4; ++cc) t[cc] = tw[cc * 132 + row];
            *(ushort4_t*)((char*)sX + swzX(row, cb)) = t;
        }
    }
}

// One K-chunk (64 c) of MFMA — round-7 form, NO explicit prefetch (the compiler
// schedules these loads better than any hand pipeline we tried; m141 lesson).
// W B-fragments from global in PRE-PACKED fragment order Wb2[ob][cb][lane][8]
// -> base + lane*16B = one fully-coalesced 1KB dwordx4 per wave (L2-resident).
// A = x (M=l) from LDS, B = W (N=o). acc[mf][nf] row=l col=o.
__device__ __forceinline__ void mfma_chunk_frag(const ushortT* sX, const ushortT* __restrict__ Wb2,
                                                int otile, f32x4 acc[4][4],
                                                int wr, int wc, int lane, int kb)
{
    const int am = wr * 64 + (lane & 15);
    const int kg = (lane >> 4) * 16;   // byte offset of this lane's k-group (LDS)
#pragma unroll
    for (int s = 0; s < 2; ++s) {
        const int cb = kb * 2 + s;
        bf16x8 a[4], b[4];
#pragma unroll
        for (int nf = 0; nf < 4; ++nf) {
            const int ob = otile * 8 + wc * 4 + nf;
            b[nf] = *(const bf16x8*)(Wb2 + (((size_t)ob * 8 + cb) * 64 + lane) * 8);
        }
#pragma unroll
        for (int mf = 0; mf < 4; ++mf)
            a[mf] = *(const bf16x8*)((const char*)sX + swzX(am + mf * 16, kb * 128 + s * 64 + kg));
#pragma unroll
        for (int mf = 0; mf < 4; ++mf)
#pragma unroll
            for (int nf = 0; nf < 4; ++nf)
                acc[mf][nf] = __builtin_amdgcn_mfma_f32_16x16x32_bf16(a[mf], b[nf], acc[mf][nf], 0, 0, 0);
    }
}

// ---------------------------------------------------------------------------
// QKV fused (round-7 verbatim, UNTOUCHED): stage x-tile once (ONE barrier),
// then 6 barrier-free GEMM-tiles with coalesced fragment-order W loads.
// Wq/Wk epilogue: per-o sum & max over l -> atomics. Wv: bias + bf16 store
// to vbuf[z][c][l] (the write pattern measured at ~ideal WRITE_SIZE).
// ---------------------------------------------------------------------------
__global__ __launch_bounds__(256, 2)
void qkv_kernel(const float* __restrict__ x, const ushortT* __restrict__ Wbf,
                const float* __restrict__ bv,
                float* __restrict__ qsum, unsigned* __restrict__ qmax,
                float* __restrict__ ksum, unsigned* __restrict__ kmax,
                ushortT* __restrict__ vbuf)
{
    __shared__ ushortT sX[LT * 256];    // 64 KiB (only LDS)
    const int tid = threadIdx.x;
    const int lane = tid & 63;
    const int wv = tid >> 6;
    const int wr = wv >> 1, wc = wv & 1;
    const int lbase = blockIdx.x * LT;
    const int z = blockIdx.y;
    const int n = z >> 4;

    stage_x_f32(x, sX, z, lbase, tid);
    __syncthreads();                    // the only barrier

    const f32x4 z4 = {0.f, 0.f, 0.f, 0.f};

    for (int w = 0; w < 3; ++w) {
        const ushortT* Wb2 = Wbf + ((size_t)w * NBR + n) * CHN * CHN;
        for (int ot = 0; ot < 2; ++ot) {
            f32x4 acc[4][4];
#pragma unroll
            for (int mf = 0; mf < 4; ++mf)
#pragma unroll
                for (int nf = 0; nf < 4; ++nf) acc[mf][nf] = z4;
#pragma unroll
            for (int kb = 0; kb < 4; ++kb)
                mfma_chunk_frag(sX, Wb2, ot, acc, wr, wc, lane, kb);

            const int obase = ot * 128;
            if (w < 2) {
                float* rs = (w == 0) ? qsum : ksum;
                unsigned* rm = (w == 0) ? qmax : kmax;
#pragma unroll
                for (int nf = 0; nf < 4; ++nf) {
                    float s = 0.f, m = -3.4e38f;
#pragma unroll
                    for (int mf = 0; mf < 4; ++mf)
#pragma unroll
                        for (int r = 0; r < 4; ++r) {
                            float v = acc[mf][nf][r];
                            s += v; m = fmaxf(m, v);
                        }
                    s += __shfl_xor(s, 16); s += __shfl_xor(s, 32);
                    m = fmaxf(m, __shfl_xor(m, 16)); m = fmaxf(m, __shfl_xor(m, 32));
                    if (lane < 16) {
                        int o = obase + wc * 64 + nf * 16 + lane;
                        atomicAdd(&rs[z * CHN + o], s);
                        atomicMax(&rm[z * CHN + o], encf(m));
                    }
                }
            } else {
#pragma unroll
                for (int nf = 0; nf < 4; ++nf) {
                    int o = obase + wc * 64 + nf * 16 + (lane & 15);
                    float bvv = bv[n * CHN + o];
#pragma unroll
                    for (int mf = 0; mf < 4; ++mf) {
                        int l = lbase + wr * 64 + mf * 16 + ((lane >> 4) << 2);
                        ushort4_t u;
#pragma unroll
                        for (int r = 0; r < 4; ++r) u[r] = f2bf(acc[mf][nf][r] + bvv);
                        *(ushort4_t*)(vbuf + (size_t)(z * CHN + o) * LEN + l) = u;
                    }
                }
            }
        }
    }
}

// ---------------------------------------------------------------------------
// O GEMM with FUSED aggregation: staging combines the 4 v-slices with attn
// weights in-register; round-15: scratch-transpose staging (vector reads AND
// conflict-free LDS writes). GEMM core is round-7 verbatim. 1 barrier.
// out_pre[z][c][l] + BN partial stats.
// ---------------------------------------------------------------------------
__global__ __launch_bounds__(256, 2)
void ogemm_kernel(const ushortT* __restrict__ v, const ushortT* __restrict__ Wbo,
                  const float* __restrict__ attn, const float* __restrict__ bo_,
                  float* __restrict__ bnsum, float* __restrict__ bnss,
                  ushortT* __restrict__ outpre)
{
    __shared__ ushortT sX[LT * 256];    // 64 KiB
    __shared__ ushortT sT[4 * 528];     // 4.2 KiB wave-private transpose scratch
    const int tid = threadIdx.x;
    const int lane = tid & 63;
    const int wv = tid >> 6;
    const int wr = wv >> 1, wc = wv & 1;
    const int lbase = blockIdx.x * LT;
    const int z = blockIdx.y;
    const int n = z >> 4;          // output branch i
    const int b_ = z & 15;
    const ushortT* Wb2 = Wbo + (size_t)n * CHN * CHN;   // per-branch slice

    float aj[4];
#pragma unroll
    for (int j = 0; j < 4; ++j) aj[j] = attn[(n * 4 + j) * BSZ + b_];

    stage_agg(v, sX, sT, aj, b_, lbase, tid);
    __syncthreads();                    // the only barrier

    const f32x4 z4 = {0.f, 0.f, 0.f, 0.f};
    for (int ot = 0; ot < 2; ++ot) {
        f32x4 acc[4][4];
#pragma unroll
        for (int mf = 0; mf < 4; ++mf)
#pragma unroll
            for (int nf = 0; nf < 4; ++nf) acc[mf][nf] = z4;
#pragma unroll
        for (int kb = 0; kb < 4; ++kb)
            mfma_chunk_frag(sX, Wb2, ot, acc, wr, wc, lane, kb);

        const int obase = ot * 128;
#pragma unroll
        for (int nf = 0; nf < 4; ++nf) {
            int o = obase + wc * 64 + nf * 16 + (lane & 15);
            float bb = bo_[n * CHN + o];
            float s = 0.f, q2 = 0.f;
#pragma unroll
            for (int mf = 0; mf < 4; ++mf) {
                int l = lbase + wr * 64 + mf * 16 + ((lane >> 4) << 2);
                ushort4_t u;
#pragma unroll
                for (int r = 0; r < 4; ++r) {
                    float vv = acc[mf][nf][r] + bb;
                    u[r] = f2bf(vv);
                    s += vv; q2 += vv * vv;
                }
                *(ushort4_t*)(outpre + (size_t)(z * CHN + o) * LEN + l) = u;
            }
            s += __shfl_xor(s, 16); s += __shfl_xor(s, 32);
            q2 += __shfl_xor(q2, 16); q2 += __shfl_xor(q2, 32);
            if (lane < 16) {
                atomicAdd(&bnsum[n * CHN + o], s);
                atomicAdd(&bnss[n * CHN + o], q2);
            }
        }
    }
}

// convert all 4 weight tensors fp32 -> bf16 in MFMA-FRAGMENT order:
// Wbf[w][n][ob][cb][lane][8] with o = ob*16 + (lane&15), c = cb*32 + (lane>>4)*8 + j
__global__ void wcvt_kernel(const float* __restrict__ Wq, const float* __restrict__ Wk,
                            const float* __restrict__ Wv, const float* __restrict__ Wo,
                            ushortT* __restrict__ Wbf)
{
    int t = blockIdx.x * 256 + threadIdx.x;    // one thread per 8-elem fragment slice
    if (t < 4 * (W_EL / 8)) {
        const float* srcs[4] = {Wq, Wk, Wv, Wo};
        int w    = t >> 15;          // W_EL/8 = 32768 per tensor
        int r    = t & 32767;
        int lane = r & 63;
        int cb   = (r >> 6) & 7;
        int ob   = (r >> 9) & 15;
        int n    = r >> 13;
        const float* src = srcs[w] + (size_t)n * CHN * CHN;
        int o = ob * 16 + (lane & 15);
        int c = cb * 32 + (lane >> 4) * 8;
        float4 f0 = *(const float4*)(src + (size_t)o * CHN + c);
        float4 f1 = *(const float4*)(src + (size_t)o * CHN + c + 4);
        ushort8_t u = {f2bf(f0.x), f2bf(f0.y), f2bf(f0.z), f2bf(f0.w),
                       f2bf(f1.x), f2bf(f1.y), f2bf(f1.z), f2bf(f1.w)};
        *(ushort8_t*)(Wbf + ((size_t)w * NBR + n) * CHN * CHN
                          + (((size_t)ob * 8 + cb) * 64 + lane) * 8) = u;
    }
}

// ---------------------------------------------------------------------------
// attention coefficients: scores[i,j,b] = (sum_c sq*sk) * edge_w[i,j] / 64
// attn[i,j,b] = softmax_j(scores) * softmax(branch_imp)[j]
// sq = qsum/L + dec(qmax) + 2*bq  (mean+max, bias shifts both by bq)
// ---------------------------------------------------------------------------
__global__ void attn_kernel(const float* __restrict__ qsum, const unsigned* __restrict__ qmax,
                            const float* __restrict__ ksum, const unsigned* __restrict__ kmax,
                            const float* __restrict__ bq, const float* __restrict__ bk,
                            const float* __restrict__ edge, const float* __restrict__ bimp,
                            float* __restrict__ attn)
{
    __shared__ float sc[NBR][NBR][BSZ];
    int tid = threadIdx.x;           // 256 threads == 4*4*16
    int i = tid >> 6, j = (tid >> 4) & 3, b = tid & 15;
    float s = 0.f;
    const float invL = 1.0f / (float)LEN;
    for (int c = 0; c < CHN; ++c) {
        int qi = (i * BSZ + b) * CHN + c;
        int ki = (j * BSZ + b) * CHN + c;
        float sq = qsum[qi] * invL + decf(qmax[qi]) + 2.f * bq[i * CHN + c];
        float sk = ksum[ki] * invL + decf(kmax[ki]) + 2.f * bk[j * CHN + c];
        s += sq * sk;
    }
    sc[i][j][b] = s * edge[i * 4 + j] * (1.0f / 64.0f);
    __syncthreads();
    if (tid < 64) {
        int ii = tid >> 4, bb = tid & 15;
        float m = -3.4e38f;
        for (int jj = 0; jj < 4; ++jj) m = fmaxf(m, sc[ii][jj][bb]);
        float e[4]; float sum = 0.f;
        for (int jj = 0; jj < 4; ++jj) { e[jj] = __expf(sc[ii][jj][bb] - m); sum += e[jj]; }
        float bm = fmaxf(fmaxf(bimp[0], bimp[1]), fmaxf(bimp[2], bimp[3]));
        float be[4]; float bs = 0.f;
        for (int jj = 0; jj < 4; ++jj) { be[jj] = __expf(bimp[jj] - bm); bs += be[jj]; }
        for (int jj = 0; jj < 4; ++jj)
            attn[(ii * 4 + jj) * BSZ + bb] = (e[jj] / sum) * (be[jj] / bs);
    }
}

// finalize BN affine: scale = gamma*rsqrt(var+eps), shift = beta - mean*scale
__global__ void bnfin_kernel(const float* __restrict__ bnsum, const float* __restrict__ bnss,
                             const float* __restrict__ gamma, const float* __restrict__ beta,
                             float* __restrict__ scl, float* __restrict__ shf)
{
    int t = blockIdx.x * blockDim.x + threadIdx.x;   // 0..1023 = n*256+c
    if (t < NBR * CHN) {
        const float inv = 1.0f / (float)BL;
        float mean = bnsum[t] * inv;
        float var = bnss[t] * inv - mean * mean;
        float rs = rsqrtf(var + BN_EPS);
        float s = gamma[t] * rs;
        scl[t] = s;
        shf[t] = beta[t] - mean * s;
    }
}

// out = relu(out_pre*scale + shift) + x
__global__ __launch_bounds__(256)
void final_kernel(const ushortT* __restrict__ outpre, const float* __restrict__ x,
                  const float* __restrict__ scl, const float* __restrict__ shf,
                  float* __restrict__ out)
{
    const long long U = (long long)NB_B * CHN * (LEN / 8);   // 8,388,608 units of 8
    for (long long u = (long long)blockIdx.x * blockDim.x + threadIdx.x; u < U;
         u += (long long)gridDim.x * blockDim.x) {
        int l0 = (int)(u & 511) * 8;
        int c  = (int)(u >> 9) & 255;
        int zz = (int)(u >> 17);          // n*16+b
        int n  = zz >> 4;
        size_t base = ((size_t)zz * CHN + c) * LEN + l0;
        ushort8_t op = *(const ushort8_t*)(outpre + base);
        float4 x0 = *(const float4*)(x + base);
        float4 x1 = *(const float4*)(x + base + 4);
        float sc = scl[n * CHN + c];
        float sh = shf[n * CHN + c];
        float xr[8] = {x0.x, x0.y, x0.z, x0.w, x1.x, x1.y, x1.z, x1.w};
        float res[8];
#pragma unroll
        for (int e = 0; e < 8; ++e) {
            float bn = bf2f(op[e]) * sc + sh;
            res[e] = fmaxf(bn, 0.f) + xr[e];
        }
        float4 o0 = {res[0], res[1], res[2], res[3]};
        float4 o1 = {res[4], res[5], res[6], res[7]};
        *(float4*)(out + base) = o0;
        *(float4*)(out + base + 4) = o1;
    }
}

extern "C" void kernel_launch(void* const* d_in, const int* in_sizes, int n_in,
                              void* d_out, int out_size, void* d_ws, size_t ws_size,
                              hipStream_t stream)
{
    const float* x     = (const float*)d_in[0];
    const float* Wq    = (const float*)d_in[1];
    const float* bq    = (const float*)d_in[2];
    const float* Wk    = (const float*)d_in[3];
    const float* bk    = (const float*)d_in[4];
    const float* Wv    = (const float*)d_in[5];
    const float* bv    = (const float*)d_in[6];
    const float* Wo    = (const float*)d_in[7];
    const float* bo    = (const float*)d_in[8];
    const float* gamma = (const float*)d_in[9];
    const float* beta  = (const float*)d_in[10];
    const float* edge  = (const float*)d_in[11];
    const float* bimp  = (const float*)d_in[12];

    char* ws = (char*)d_ws;
    const size_t P_BYTES = (size_t)NBR * BSZ * CHN * LEN * 2;   // 128 MiB (bf16)
    ushortT* outpre = (ushortT*)ws;          // out_pre staging (ws[0:128Mi])
    size_t off = P_BYTES;
    float*    qsum = (float*)(ws + off);    off += 65536;
    unsigned* qmax = (unsigned*)(ws + off); off += 65536;
    float*    ksum = (float*)(ws + off);    off += 65536;
    unsigned* kmax = (unsigned*)(ws + off); off += 65536;
    float*    attn = (float*)(ws + off);    off += 1024;
    float*    bnsum= (float*)(ws + off);    off += 4096;
    float*    bnss = (float*)(ws + off);    off += 4096;
    float*    scl  = (float*)(ws + off);    off += 4096;
    float*    shf  = (float*)(ws + off);    off += 4096;

    // zero the small accumulators (sum=0; max uses encoding where 0 < enc(-inf))
    hipMemsetAsync(ws + P_BYTES, 0, off - P_BYTES, stream);

    // d_out scratch (all dead before final_kernel rewrites d_out):
    //   [0, 128Mi):    v (bf16, [z][c][l]) written by qkv, read by ogemm
    //   [128Mi, +2Mi): Wbf (bf16 weights, fragment order) written by wcvt
    ushortT* vbuf = (ushortT*)d_out;
    ushortT* Wbf  = (ushortT*)((char*)d_out + ((size_t)134217728));
    float*   outf = (float*)d_out;

    wcvt_kernel<<<(4 * (W_EL / 8) + 255) / 256, 256, 0, stream>>>(Wq, Wk, Wv, Wo, Wbf);

    dim3 gq(LEN / LT, NB_B);   // (32, 64)
    qkv_kernel<<<gq, 256, 0, stream>>>(x, Wbf, bv, qsum, qmax, ksum, kmax, vbuf);
    attn_kernel<<<1, 256, 0, stream>>>(qsum, qmax, ksum, kmax, bq, bk, edge, bimp, attn);
    ogemm_kernel<<<gq, 256, 0, stream>>>(vbuf, Wbf + (size_t)3 * W_EL, attn, bo, bnsum, bnss, outpre);
    bnfin_kernel<<<4, 256, 0, stream>>>(bnsum, bnss, gamma, beta, scl, shf);
    final_kernel<<<8192, 256, 0, stream>>>(outpre, x, scl, shf, outf);
}

// Round 16
// 488.656 us; speedup vs baseline: 1.8362x; 1.0083x over previous
//
#include <hip/hip_runtime.h>
#include <stdint.h>
#include <stddef.h>

// Problem constants (reference: NB=4, B=16, C=256, L=4096)
#define NBR 4
#define BSZ 16
#define CHN 256
#define LEN 4096
#define NB_B 64            // NBR*BSZ
#define BL   65536         // BSZ*LEN
#define BN_EPS 1e-5f
#define W_EL (NBR*CHN*CHN) // 262144 elements per weight tensor
#define LT   128           // l-tile (round-7 value: the only L2-clean shape)

typedef unsigned short ushortT;
typedef unsigned short ushort4_t __attribute__((ext_vector_type(4)));
typedef unsigned short ushort8_t __attribute__((ext_vector_type(8)));
typedef short bf16x8 __attribute__((ext_vector_type(8)));
typedef float f32x4 __attribute__((ext_vector_type(4)));

__device__ __forceinline__ float bf2f(ushortT u) {
    return __uint_as_float(((unsigned)u) << 16);
}
__device__ __forceinline__ ushortT f2bf(float f) {
    unsigned b = __float_as_uint(f);
    return (ushortT)((b + 0x7FFFu + ((b >> 16) & 1u)) >> 16);
}
// order-preserving float->uint encoding (monotone); memset-0 init is below enc(-inf)
__device__ __forceinline__ unsigned encf(float f) {
    unsigned b = __float_as_uint(f);
    return (b & 0x80000000u) ? ~b : (b | 0x80000000u);
}
__device__ __forceinline__ float decf(unsigned u) {
    unsigned b = (u & 0x80000000u) ? (u ^ 0x80000000u) : ~u;
    return __uint_as_float(b);
}

// LDS swizzle for sX (byte offsets). Rows are 512B (256 c bf16). row in 0..127.
// XOR terms are 16B/128B-aligned, so 8B-aligned sub-writes stay consistent
// with the 16B-aligned fragment reads.
__device__ __forceinline__ int swzX(int row, int cb) {
    return row * 512 + (cb ^ ((row & 7) << 4) ^ (((row >> 3) & 3) << 7));
}

// Stage x-tile [l=128][c=256] into LDS, transposed+converted, swizzled.
// Loads are coalesced per wave-instruction (lane -> l).
__device__ __forceinline__ void stage_x_f32(const float* x, ushortT* sX, int z, int lbase, int tid)
{
    const int ls = tid & 127;
    const int gh = tid >> 7;
    const float* xp = x + (size_t)z * CHN * LEN + lbase + ls;
#pragma unroll
    for (int g = 0; g < 16; ++g) {
        int c0 = (gh * 16 + g) * 8;
        ushort8_t u;
#pragma unroll
        for (int i = 0; i < 8; ++i) u[i] = f2bf(xp[(size_t)(c0 + i) * LEN]);
        *(ushort8_t*)((char*)sX + swzX(ls, c0 * 2)) = u;
    }
}

// Fused-agg staging (round-15 form): vector global reads (16B along l,
// coalesced) + conflict-free LDS writes via a per-wave scratch transpose.
__device__ __forceinline__ void stage_agg(const ushortT* v, ushortT* sX, ushortT* sT,
                                          const float aj[4], int b_, int lbase, int tid)
{
    const int lane = tid & 63;
    const int wave = tid >> 6;
    const int c4   = lane >> 4;        // 0..3: c within the wave's 4-c group
    const int lg   = lane & 15;        // l-octet
    ushortT* tw = sT + wave * 528;     // 1056B per wave, rows padded to 264B
    const ushortT* vb0 = v + (size_t)(0 * BSZ + b_) * CHN * LEN;
    const ushortT* vb1 = v + (size_t)(1 * BSZ + b_) * CHN * LEN;
    const ushortT* vb2 = v + (size_t)(2 * BSZ + b_) * CHN * LEN;
    const ushortT* vb3 = v + (size_t)(3 * BSZ + b_) * CHN * LEN;
#pragma unroll 2
    for (int pass = 0; pass < 16; ++pass) {
        const int c = pass * 16 + wave * 4 + c4;
        const size_t base = (size_t)c * LEN + lbase + lg * 8;
        ushort8_t r0 = *(const ushort8_t*)(vb0 + base);
        ushort8_t r1 = *(const ushort8_t*)(vb1 + base);
        ushort8_t r2 = *(const ushort8_t*)(vb2 + base);
        ushort8_t r3 = *(const ushort8_t*)(vb3 + base);
        ushort8_t u;
#pragma unroll
        for (int e = 0; e < 8; ++e) {
            float s = aj[0] * bf2f(r0[e]) + aj[1] * bf2f(r1[e])
                    + aj[2] * bf2f(r2[e]) + aj[3] * bf2f(r3[e]);
            u[e] = f2bf(s);
        }
        *(ushort8_t*)(tw + c4 * 132 + lg * 8) = u;      // l-contiguous scratch write

        const int cb = pass * 32 + wave * 8;             // byte offset of 4-c group
#pragma unroll
        for (int sub = 0; sub < 2; ++sub) {
            const int row = sub * 64 + lane;             // 0..127
            ushort4_t t;
#pragma unroll
            for (int cc = 0; cc < 4; ++cc) t[cc] = tw[cc * 132 + row];
            *(ushort4_t*)((char*)sX + swzX(row, cb)) = t;
        }
    }
}

// One K-chunk (64 c) of MFMA — round-7 form, NO explicit prefetch (the compiler
// schedules these loads better than any hand pipeline we tried; m141 lesson).
// W B-fragments from global in PRE-PACKED fragment order Wb2[ob][cb][lane][8]
// -> base + lane*16B = one fully-coalesced 1KB dwordx4 per wave (L2-resident).
// A = x (M=l) from LDS, B = W (N=o). acc[mf][nf] row=l col=o.
__device__ __forceinline__ void mfma_chunk_frag(const ushortT* sX, const ushortT* __restrict__ Wb2,
                                                int otile, f32x4 acc[4][4],
                                                int wr, int wc, int lane, int kb)
{
    const int am = wr * 64 + (lane & 15);
    const int kg = (lane >> 4) * 16;   // byte offset of this lane's k-group (LDS)
#pragma unroll
    for (int s = 0; s < 2; ++s) {
        const int cb = kb * 2 + s;
        bf16x8 a[4], b[4];
#pragma unroll
        for (int nf = 0; nf < 4; ++nf) {
            const int ob = otile * 8 + wc * 4 + nf;
            b[nf] = *(const bf16x8*)(Wb2 + (((size_t)ob * 8 + cb) * 64 + lane) * 8);
        }
#pragma unroll
        for (int mf = 0; mf < 4; ++mf)
            a[mf] = *(const bf16x8*)((const char*)sX + swzX(am + mf * 16, kb * 128 + s * 64 + kg));
#pragma unroll
        for (int mf = 0; mf < 4; ++mf)
#pragma unroll
            for (int nf = 0; nf < 4; ++nf)
                acc[mf][nf] = __builtin_amdgcn_mfma_f32_16x16x32_bf16(a[mf], b[nf], acc[mf][nf], 0, 0, 0);
    }
}

// ---------------------------------------------------------------------------
// QKV fused (round-7 verbatim, UNTOUCHED): stage x-tile once (ONE barrier),
// then 6 barrier-free GEMM-tiles with coalesced fragment-order W loads.
// Wq/Wk epilogue: per-o sum & max over l -> atomics. Wv: bias + bf16 store
// to vbuf[z][c][l] (the write pattern measured at ~ideal WRITE_SIZE).
// ---------------------------------------------------------------------------
__global__ __launch_bounds__(256, 2)
void qkv_kernel(const float* __restrict__ x, const ushortT* __restrict__ Wbf,
                const float* __restrict__ bv,
                float* __restrict__ qsum, unsigned* __restrict__ qmax,
                float* __restrict__ ksum, unsigned* __restrict__ kmax,
                ushortT* __restrict__ vbuf)
{
    __shared__ ushortT sX[LT * 256];    // 64 KiB (only LDS)
    const int tid = threadIdx.x;
    const int lane = tid & 63;
    const int wv = tid >> 6;
    const int wr = wv >> 1, wc = wv & 1;
    const int lbase = blockIdx.x * LT;
    const int z = blockIdx.y;
    const int n = z >> 4;

    stage_x_f32(x, sX, z, lbase, tid);
    __syncthreads();                    // the only barrier

    const f32x4 z4 = {0.f, 0.f, 0.f, 0.f};

    for (int w = 0; w < 3; ++w) {
        const ushortT* Wb2 = Wbf + ((size_t)w * NBR + n) * CHN * CHN;
        for (int ot = 0; ot < 2; ++ot) {
            f32x4 acc[4][4];
#pragma unroll
            for (int mf = 0; mf < 4; ++mf)
#pragma unroll
                for (int nf = 0; nf < 4; ++nf) acc[mf][nf] = z4;
#pragma unroll
            for (int kb = 0; kb < 4; ++kb)
                mfma_chunk_frag(sX, Wb2, ot, acc, wr, wc, lane, kb);

            const int obase = ot * 128;
            if (w < 2) {
                float* rs = (w == 0) ? qsum : ksum;
                unsigned* rm = (w == 0) ? qmax : kmax;
#pragma unroll
                for (int nf = 0; nf < 4; ++nf) {
                    float s = 0.f, m = -3.4e38f;
#pragma unroll
                    for (int mf = 0; mf < 4; ++mf)
#pragma unroll
                        for (int r = 0; r < 4; ++r) {
                            float v = acc[mf][nf][r];
                            s += v; m = fmaxf(m, v);
                        }
                    s += __shfl_xor(s, 16); s += __shfl_xor(s, 32);
                    m = fmaxf(m, __shfl_xor(m, 16)); m = fmaxf(m, __shfl_xor(m, 32));
                    if (lane < 16) {
                        int o = obase + wc * 64 + nf * 16 + lane;
                        atomicAdd(&rs[z * CHN + o], s);
                        atomicMax(&rm[z * CHN + o], encf(m));
                    }
                }
            } else {
#pragma unroll
                for (int nf = 0; nf < 4; ++nf) {
                    int o = obase + wc * 64 + nf * 16 + (lane & 15);
                    float bvv = bv[n * CHN + o];
#pragma unroll
                    for (int mf = 0; mf < 4; ++mf) {
                        int l = lbase + wr * 64 + mf * 16 + ((lane >> 4) << 2);
                        ushort4_t u;
#pragma unroll
                        for (int r = 0; r < 4; ++r) u[r] = f2bf(acc[mf][nf][r] + bvv);
                        *(ushort4_t*)(vbuf + (size_t)(z * CHN + o) * LEN + l) = u;
                    }
                }
            }
        }
    }
}

// ---------------------------------------------------------------------------
// O GEMM, 4-BRANCH MERGED (round-16 change): one block per (l-tile, b_)
// loops over the 4 output branches i. The 4 v-slices are HBM-fetched once
// (i=0) and L2/L3-hit for i=1..3 — kills the cross-block v re-fetch that
// round-13 counters showed (FETCH 265MB vs 128MB ideal). Per branch:
// stage_agg(aj_i) -> barrier -> Wo(i) GEMM -> epilogue -> barrier.
// ---------------------------------------------------------------------------
__global__ __launch_bounds__(256, 2)
void ogemm_kernel(const ushortT* __restrict__ v, const ushortT* __restrict__ Wbo,
                  const float* __restrict__ attn, const float* __restrict__ bo_,
                  float* __restrict__ bnsum, float* __restrict__ bnss,
                  ushortT* __restrict__ outpre)
{
    __shared__ ushortT sX[LT * 256];    // 64 KiB
    __shared__ ushortT sT[4 * 528];     // 4.2 KiB wave-private transpose scratch
    const int tid = threadIdx.x;
    const int lane = tid & 63;
    const int wv = tid >> 6;
    const int wr = wv >> 1, wc = wv & 1;
    const int lbase = blockIdx.x * LT;
    const int b_ = blockIdx.y;          // 0..15
    const f32x4 z4 = {0.f, 0.f, 0.f, 0.f};

    for (int i = 0; i < NBR; ++i) {     // output branch
        const int z = i * BSZ + b_;
        const ushortT* Wb2 = Wbo + (size_t)i * CHN * CHN;

        float aj[4];
#pragma unroll
        for (int j = 0; j < 4; ++j) aj[j] = attn[(i * 4 + j) * BSZ + b_];

        if (i) __syncthreads();         // previous GEMM done reading sX
        stage_agg(v, sX, sT, aj, b_, lbase, tid);
        __syncthreads();                // sX ready

        for (int ot = 0; ot < 2; ++ot) {
            f32x4 acc[4][4];
#pragma unroll
            for (int mf = 0; mf < 4; ++mf)
#pragma unroll
                for (int nf = 0; nf < 4; ++nf) acc[mf][nf] = z4;
#pragma unroll
            for (int kb = 0; kb < 4; ++kb)
                mfma_chunk_frag(sX, Wb2, ot, acc, wr, wc, lane, kb);

            const int obase = ot * 128;
#pragma unroll
            for (int nf = 0; nf < 4; ++nf) {
                int o = obase + wc * 64 + nf * 16 + (lane & 15);
                float bb = bo_[i * CHN + o];
                float s = 0.f, q2 = 0.f;
#pragma unroll
                for (int mf = 0; mf < 4; ++mf) {
                    int l = lbase + wr * 64 + mf * 16 + ((lane >> 4) << 2);
                    ushort4_t u;
#pragma unroll
                    for (int r = 0; r < 4; ++r) {
                        float vv = acc[mf][nf][r] + bb;
                        u[r] = f2bf(vv);
                        s += vv; q2 += vv * vv;
                    }
                    *(ushort4_t*)(outpre + (size_t)(z * CHN + o) * LEN + l) = u;
                }
                s += __shfl_xor(s, 16); s += __shfl_xor(s, 32);
                q2 += __shfl_xor(q2, 16); q2 += __shfl_xor(q2, 32);
                if (lane < 16) {
                    atomicAdd(&bnsum[i * CHN + o], s);
                    atomicAdd(&bnss[i * CHN + o], q2);
                }
            }
        }
    }
}

// convert all 4 weight tensors fp32 -> bf16 in MFMA-FRAGMENT order:
// Wbf[w][n][ob][cb][lane][8] with o = ob*16 + (lane&15), c = cb*32 + (lane>>4)*8 + j
__global__ void wcvt_kernel(const float* __restrict__ Wq, const float* __restrict__ Wk,
                            const float* __restrict__ Wv, const float* __restrict__ Wo,
                            ushortT* __restrict__ Wbf)
{
    int t = blockIdx.x * 256 + threadIdx.x;    // one thread per 8-elem fragment slice
    if (t < 4 * (W_EL / 8)) {
        const float* srcs[4] = {Wq, Wk, Wv, Wo};
        int w    = t >> 15;          // W_EL/8 = 32768 per tensor
        int r    = t & 32767;
        int lane = r & 63;
        int cb   = (r >> 6) & 7;
        int ob   = (r >> 9) & 15;
        int n    = r >> 13;
        const float* src = srcs[w] + (size_t)n * CHN * CHN;
        int o = ob * 16 + (lane & 15);
        int c = cb * 32 + (lane >> 4) * 8;
        float4 f0 = *(const float4*)(src + (size_t)o * CHN + c);
        float4 f1 = *(const float4*)(src + (size_t)o * CHN + c + 4);
        ushort8_t u = {f2bf(f0.x), f2bf(f0.y), f2bf(f0.z), f2bf(f0.w),
                       f2bf(f1.x), f2bf(f1.y), f2bf(f1.z), f2bf(f1.w)};
        *(ushort8_t*)(Wbf + ((size_t)w * NBR + n) * CHN * CHN
                          + (((size_t)ob * 8 + cb) * 64 + lane) * 8) = u;
    }
}

// ---------------------------------------------------------------------------
// attention coefficients: scores[i,j,b] = (sum_c sq*sk) * edge_w[i,j] / 64
// attn[i,j,b] = softmax_j(scores) * softmax(branch_imp)[j]
// sq = qsum/L + dec(qmax) + 2*bq  (mean+max, bias shifts both by bq)
// ---------------------------------------------------------------------------
__global__ void attn_kernel(const float* __restrict__ qsum, const unsigned* __restrict__ qmax,
                            const float* __restrict__ ksum, const unsigned* __restrict__ kmax,
                            const float* __restrict__ bq, const float* __restrict__ bk,
                            const float* __restrict__ edge, const float* __restrict__ bimp,
                            float* __restrict__ attn)
{
    __shared__ float sc[NBR][NBR][BSZ];
    int tid = threadIdx.x;           // 256 threads == 4*4*16
    int i = tid >> 6, j = (tid >> 4) & 3, b = tid & 15;
    float s = 0.f;
    const float invL = 1.0f / (float)LEN;
    for (int c = 0; c < CHN; ++c) {
        int qi = (i * BSZ + b) * CHN + c;
        int ki = (j * BSZ + b) * CHN + c;
        float sq = qsum[qi] * invL + decf(qmax[qi]) + 2.f * bq[i * CHN + c];
        float sk = ksum[ki] * invL + decf(kmax[ki]) + 2.f * bk[j * CHN + c];
        s += sq * sk;
    }
    sc[i][j][b] = s * edge[i * 4 + j] * (1.0f / 64.0f);
    __syncthreads();
    if (tid < 64) {
        int ii = tid >> 4, bb = tid & 15;
        float m = -3.4e38f;
        for (int jj = 0; jj < 4; ++jj) m = fmaxf(m, sc[ii][jj][bb]);
        float e[4]; float sum = 0.f;
        for (int jj = 0; jj < 4; ++jj) { e[jj] = __expf(sc[ii][jj][bb] - m); sum += e[jj]; }
        float bm = fmaxf(fmaxf(bimp[0], bimp[1]), fmaxf(bimp[2], bimp[3]));
        float be[4]; float bs = 0.f;
        for (int jj = 0; jj < 4; ++jj) { be[jj] = __expf(bimp[jj] - bm); bs += be[jj]; }
        for (int jj = 0; jj < 4; ++jj)
            attn[(ii * 4 + jj) * BSZ + bb] = (e[jj] / sum) * (be[jj] / bs);
    }
}

// finalize BN affine: scale = gamma*rsqrt(var+eps), shift = beta - mean*scale
__global__ void bnfin_kernel(const float* __restrict__ bnsum, const float* __restrict__ bnss,
                             const float* __restrict__ gamma, const float* __restrict__ beta,
                             float* __restrict__ scl, float* __restrict__ shf)
{
    int t = blockIdx.x * blockDim.x + threadIdx.x;   // 0..1023 = n*256+c
    if (t < NBR * CHN) {
        const float inv = 1.0f / (float)BL;
        float mean = bnsum[t] * inv;
        float var = bnss[t] * inv - mean * mean;
        float rs = rsqrtf(var + BN_EPS);
        float s = gamma[t] * rs;
        scl[t] = s;
        shf[t] = beta[t] - mean * s;
    }
}

// out = relu(out_pre*scale + shift) + x
__global__ __launch_bounds__(256)
void final_kernel(const ushortT* __restrict__ outpre, const float* __restrict__ x,
                  const float* __restrict__ scl, const float* __restrict__ shf,
                  float* __restrict__ out)
{
    const long long U = (long long)NB_B * CHN * (LEN / 8);   // 8,388,608 units of 8
    for (long long u = (long long)blockIdx.x * blockDim.x + threadIdx.x; u < U;
         u += (long long)gridDim.x * blockDim.x) {
        int l0 = (int)(u & 511) * 8;
        int c  = (int)(u >> 9) & 255;
        int zz = (int)(u >> 17);          // n*16+b
        int n  = zz >> 4;
        size_t base = ((size_t)zz * CHN + c) * LEN + l0;
        ushort8_t op = *(const ushort8_t*)(outpre + base);
        float4 x0 = *(const float4*)(x + base);
        float4 x1 = *(const float4*)(x + base + 4);
        float sc = scl[n * CHN + c];
        float sh = shf[n * CHN + c];
        float xr[8] = {x0.x, x0.y, x0.z, x0.w, x1.x, x1.y, x1.z, x1.w};
        float res[8];
#pragma unroll
        for (int e = 0; e < 8; ++e) {
            float bn = bf2f(op[e]) * sc + sh;
            res[e] = fmaxf(bn, 0.f) + xr[e];
        }
        float4 o0 = {res[0], res[1], res[2], res[3]};
        float4 o1 = {res[4], res[5], res[6], res[7]};
        *(float4*)(out + base) = o0;
        *(float4*)(out + base + 4) = o1;
    }
}

extern "C" void kernel_launch(void* const* d_in, const int* in_sizes, int n_in,
                              void* d_out, int out_size, void* d_ws, size_t ws_size,
                              hipStream_t stream)
{
    const float* x     = (const float*)d_in[0];
    const float* Wq    = (const float*)d_in[1];
    const float* bq    = (const float*)d_in[2];
    const float* Wk    = (const float*)d_in[3];
    const float* bk    = (const float*)d_in[4];
    const float* Wv    = (const float*)d_in[5];
    const float* bv    = (const float*)d_in[6];
    const float* Wo    = (const float*)d_in[7];
    const float* bo    = (const float*)d_in[8];
    const float* gamma = (const float*)d_in[9];
    const float* beta  = (const float*)d_in[10];
    const float* edge  = (const float*)d_in[11];
    const float* bimp  = (const float*)d_in[12];

    char* ws = (char*)d_ws;
    const size_t P_BYTES = (size_t)NBR * BSZ * CHN * LEN * 2;   // 128 MiB (bf16)
    ushortT* outpre = (ushortT*)ws;          // out_pre staging (ws[0:128Mi])
    size_t off = P_BYTES;
    float*    qsum = (float*)(ws + off);    off += 65536;
    unsigned* qmax = (unsigned*)(ws + off); off += 65536;
    float*    ksum = (float*)(ws + off);    off += 65536;
    unsigned* kmax = (unsigned*)(ws + off); off += 65536;
    float*    attn = (float*)(ws + off);    off += 1024;
    float*    bnsum= (float*)(ws + off);    off += 4096;
    float*    bnss = (float*)(ws + off);    off += 4096;
    float*    scl  = (float*)(ws + off);    off += 4096;
    float*    shf  = (float*)(ws + off);    off += 4096;

    // zero the small accumulators (sum=0; max uses encoding where 0 < enc(-inf))
    hipMemsetAsync(ws + P_BYTES, 0, off - P_BYTES, stream);

    // d_out scratch (all dead before final_kernel rewrites d_out):
    //   [0, 128Mi):    v (bf16, [z][c][l]) written by qkv, read by ogemm
    //   [128Mi, +2Mi): Wbf (bf16 weights, fragment order) written by wcvt
    ushortT* vbuf = (ushortT*)d_out;
    ushortT* Wbf  = (ushortT*)((char*)d_out + ((size_t)134217728));
    float*   outf = (float*)d_out;

    wcvt_kernel<<<(4 * (W_EL / 8) + 255) / 256, 256, 0, stream>>>(Wq, Wk, Wv, Wo, Wbf);

    dim3 gq(LEN / LT, NB_B);   // (32, 64)
    qkv_kernel<<<gq, 256, 0, stream>>>(x, Wbf, bv, qsum, qmax, ksum, kmax, vbuf);
    attn_kernel<<<1, 256, 0, stream>>>(qsum, qmax, ksum, kmax, bq, bk, edge, bimp, attn);
    dim3 go(LEN / LT, BSZ);    // (32, 16): 512 blocks, 4 branches per block
    ogemm_kernel<<<go, 256, 0, stream>>>(vbuf, Wbf + (size_t)3 * W_EL, attn, bo, bnsum, bnss, outpre);
    bnfin_kernel<<<4, 256, 0, stream>>>(bnsum, bnss, gamma, beta, scl, shf);
    final_kernel<<<8192, 256, 0, stream>>>(outpre, x, scl, shf, outf);
}